// Round 7
// baseline (380.495 us; speedup 1.0000x reference)
//
#include <hip/hip_runtime.h>

// Problem: B=8, C=512, H=W=64, NH=8, D=64, window 8x8 (Ws=64), N=4096.
// Token dim is window-permuted AT THE LAYERNORM (bit-swap n[8:6]<->n[5:3], involution):
// qn/kvn/Q/K/V/attn-out all live in permuted space (windows contiguous); un-permute
// happens only in gemm_out's final transposed store. V stored transposed (b,h,d,wpos).
//
// Round-7: round-6 with the gemm_out staging-stride bug fixed (sOutF stride was 17
// for a 64-wide tile -> cross-row clobber + OOB; now 65 with sRes at byte 66560).
// (1) attn: 2 head-tiles of one (b,w) per block (grid 2048), all global loads issued
// up-front, tile-1 loads in flight under tile-0 compute. (2) gemm_out epilogue:
// swapb-aware coalesced f32 store — per channel the 256-row tile's tokens form 8 runs
// of 32 contiguous tokens (128B lines); stage acc+bias+residual in LDS (256x65 f32)
// per 64-col group, then store full lines. gemm_qkv/prep unchanged (controls).

typedef unsigned short u16;
typedef __bf16 bf16x8 __attribute__((ext_vector_type(8)));
typedef float f32x4 __attribute__((ext_vector_type(4)));
typedef u16 u16x8 __attribute__((ext_vector_type(8)));
typedef u16 u16x4 __attribute__((ext_vector_type(4)));

__device__ __forceinline__ u16 f2bf(float f) {
    __bf16 h = (__bf16)f;
    return __builtin_bit_cast(u16, h);
}
__device__ __forceinline__ float bf2f(u16 u) {
    return (float)__builtin_bit_cast(__bf16, u);
}
__device__ __forceinline__ f32x4 mfma16(bf16x8 a, bf16x8 b, f32x4 c) {
    return __builtin_amdgcn_mfma_f32_16x16x32_bf16(a, b, c, 0, 0, 0);
}
__device__ __forceinline__ void gl_lds16(const u16* g, u16* l) {
    __builtin_amdgcn_global_load_lds((const __attribute__((address_space(1))) void*)g,
                                     (__attribute__((address_space(3))) void*)l, 16, 0, 0);
}
// window permutation: n = hn[11:9] r[8:6] wn[5:3] cc[2:0] -> hn wn r cc  (involution)
__device__ __forceinline__ int swapb(int n) {
    return (n & 0xE07) | ((n & 0x1C0) >> 3) | ((n & 0x038) << 3);
}

// ---------------------------------------------------------------------------
// prep_kernel: grid 6144 x 256.
//  blocks [0,1024):    LayerNorm q  -> qn   (permuted bf16)
//  blocks [1024,2048): LayerNorm kv -> kvn
//  blocks [2048,6144): setup: bf16 weights, RoPE table, bias table
// ---------------------------------------------------------------------------
__global__ __launch_bounds__(256) void prep_kernel(
    const float* __restrict__ q, const float* __restrict__ kv,
    const float* __restrict__ g_q, const float* __restrict__ b_q,
    const float* __restrict__ g_kv, const float* __restrict__ b_kv,
    const float* __restrict__ Wq, const float* __restrict__ Wk,
    const float* __restrict__ Wv, const float* __restrict__ Wo,
    const float* __restrict__ btab,
    u16* __restrict__ qn, u16* __restrict__ kvn,
    u16* __restrict__ wq, u16* __restrict__ wk,
    u16* __restrict__ wv, u16* __restrict__ wo,
    float* __restrict__ rope, float* __restrict__ biasf)
{
    __shared__ u16 sX[512 * 36];  // [c][token], stride 36 (8B-aligned u16x4 stores)
    __shared__ float sS[1024];
    __shared__ float sQm[1024];
    __shared__ float sMu[32], sInv[32];

    const int bidx = blockIdx.x;
    const int tid = threadIdx.x;

    if (bidx >= 2048) {  // ---------------- setup role ----------------
        int idx = (bidx - 2048) * 256 + tid;
        {
            int w = idx >> 18, e = idx & 262143;
            const float* src = (w == 0) ? Wq : (w == 1) ? Wk : (w == 2) ? Wv : Wo;
            u16* dst = (w == 0) ? wq : (w == 1) ? wk : (w == 2) ? wv : wo;
            dst[e] = f2bf(src[e]);
        }
        if (idx < 131072) {
            int n = idx >> 5, j = idx & 31;
            float inv = powf(10000.0f, -(float)j / 32.0f);
            float a = (float)n * inv;
            float s, c;
            sincosf(a, &s, &c);
            rope[n * 64 + 2 * j] = s;
            rope[n * 64 + 2 * j + 1] = c;
        }
        if (idx < 32768) {
            int qq = idx & 63, pp = (idx >> 6) & 63, h = idx >> 12;
            int r1 = pp >> 3, c1 = pp & 7, r2 = qq >> 3, c2 = qq & 7;
            int ri = (r1 - r2 + 7) * 15 + (c1 - c2 + 7);
            biasf[idx] = btab[ri * 8 + h];
        }
        return;
    }

    // ---------------- LayerNorm role ----------------
    const float* x  = (bidx < 1024) ? q : kv;
    const float* g  = (bidx < 1024) ? g_q : g_kv;
    const float* be = (bidx < 1024) ? b_q : b_kv;
    u16* out = (bidx < 1024) ? qn : kvn;
    const int bid = bidx & 1023;

    const int b = bid >> 7, grp = bid & 127;
    const int nbase = grp << 5;
    const int t4 = tid & 7;   // token quad (4 tokens each)
    const int cg = tid >> 3;  // 32 channels per iteration

    const float* xp = x + ((size_t)b << 21) + nbase + (t4 << 2);
    float sm[4] = {0.f, 0.f, 0.f, 0.f}, sq2[4] = {0.f, 0.f, 0.f, 0.f};
#pragma unroll 4
    for (int it = 0; it < 16; it++) {
        int c = (it << 5) + cg;
        f32x4 v = *(const f32x4*)&xp[(size_t)c << 12];
        u16x4 h;
#pragma unroll
        for (int r = 0; r < 4; r++) {
            sm[r] += v[r];
            sq2[r] += v[r] * v[r];
            h[r] = f2bf(v[r]);
        }
        *(u16x4*)&sX[c * 36 + (t4 << 2)] = h;
    }
#pragma unroll
    for (int r = 0; r < 4; r++) {
        sS[tid * 4 + r] = sm[r];
        sQm[tid * 4 + r] = sq2[r];
    }
    __syncthreads();
    if (tid < 32) {  // token tid: t4v = tid>>2, r = tid&3
        int t4v = tid >> 2, r = tid & 3;
        float a = 0.f, q2 = 0.f;
#pragma unroll
        for (int c2 = 0; c2 < 32; c2++) {
            int i2 = ((c2 << 3) + t4v) * 4 + r;
            a += sS[i2];
            q2 += sQm[i2];
        }
        float mu = a * (1.f / 512.f);
        float var = q2 * (1.f / 512.f) - mu * mu;
        sMu[tid] = mu;
        sInv[tid] = rsqrtf(var + 1e-5f);
    }
    __syncthreads();

    const int t = tid >> 3;         // 0..31
    const int cs = (tid & 7) << 3;  // 0..56
    float mu = sMu[t], inv = sInv[t];
    int p = swapb(nbase + t);  // permuted row
    size_t orow = ((size_t)((b << 12) + p)) * 512;
#pragma unroll
    for (int it = 0; it < 8; it++) {
        int c0 = cs + (it << 6);
        f32x4 g0 = *(const f32x4*)&g[c0];
        f32x4 g1 = *(const f32x4*)&g[c0 + 4];
        f32x4 e0 = *(const f32x4*)&be[c0];
        f32x4 e1 = *(const f32x4*)&be[c0 + 4];
        u16x8 o;
#pragma unroll
        for (int k = 0; k < 8; k++) {
            float v = bf2f(sX[(c0 + k) * 36 + t]);
            float gg = (k < 4) ? g0[k] : g1[k - 4];
            float bb = (k < 4) ? e0[k] : e1[k - 4];
            o[k] = f2bf((v - mu) * inv * gg + bb);
        }
        *(u16x8*)&out[orow + c0] = o;
    }
}

// ---------------------------------------------------------------------------
// Shared 8-phase 256x256 / BK=64 / 8-wave main-loop machinery (round-4 verified).
// ---------------------------------------------------------------------------
#define SB() __builtin_amdgcn_sched_barrier(0)
#define BARRIER() do { SB(); __builtin_amdgcn_s_barrier(); SB(); } while (0)
#define VM4() asm volatile("s_waitcnt vmcnt(4)" ::: "memory")
#define VM0() asm volatile("s_waitcnt vmcnt(0)" ::: "memory")
#define STAGE_A(base, kt, kk) do { \
        const u16* _g = aSt + (kt) * 64 + (kk) * 32; \
        gl_lds16(_g, &smem[(base) + (kk) * 8192 + wid * 512]); \
        gl_lds16(_g + 65536, &smem[(base) + (kk) * 8192 + 4096 + wid * 512]); \
    } while (0)
#define STAGE_B(base, kt, kk) do { \
        const u16* _g = bSt + (kt) * 64 + (kk) * 32; \
        gl_lds16(_g, &smem[(base) + (kk) * 8192 + wid * 512]); \
        gl_lds16(_g + 65536, &smem[(base) + (kk) * 8192 + 4096 + wid * 512]); \
    } while (0)
#define LDA(base, kk, mh) do { \
        Af[0] = *(const bf16x8*)&smem[(base) + (kk) * 8192 + (mh) * 2048 + 0 * 512 + aOff]; \
        Af[1] = *(const bf16x8*)&smem[(base) + (kk) * 8192 + (mh) * 2048 + 1 * 512 + aOff]; \
        Af[2] = *(const bf16x8*)&smem[(base) + (kk) * 8192 + (mh) * 2048 + 2 * 512 + aOff]; \
        Af[3] = *(const bf16x8*)&smem[(base) + (kk) * 8192 + (mh) * 2048 + 3 * 512 + aOff]; \
    } while (0)
#define LDB(base, kk) do { \
        Bf[0] = *(const bf16x8*)&smem[(base) + (kk) * 8192 + 0 * 512 + bOff]; \
        Bf[1] = *(const bf16x8*)&smem[(base) + (kk) * 8192 + 1 * 512 + bOff]; \
        Bf[2] = *(const bf16x8*)&smem[(base) + (kk) * 8192 + 2 * 512 + bOff]; \
        Bf[3] = *(const bf16x8*)&smem[(base) + (kk) * 8192 + 3 * 512 + bOff]; \
    } while (0)
#define MMA(mh) do { \
        __builtin_amdgcn_s_setprio(1); \
        _Pragma("unroll") \
        for (int fi = 0; fi < 4; ++fi) \
            _Pragma("unroll") \
            for (int j = 0; j < 4; ++j) \
                acc[(mh) * 4 + fi][j] = mfma16(Af[fi], Bf[j], acc[(mh) * 4 + fi][j]); \
        __builtin_amdgcn_s_setprio(0); \
    } while (0)

#define MAIN_LOOP_8PHASE() \
    STAGE_A(AX, 0, 0); \
    STAGE_B(BX, 0, 0); \
    STAGE_A(AX, 0, 1); \
    STAGE_B(BX, 0, 1); \
    VM4(); \
    BARRIER(); \
    _Pragma("unroll") \
    for (int it = 0; it < 4; ++it) { \
        const bool last = (it == 3); \
        bf16x8 Af[4], Bf[4]; \
        LDA(AX, 0, 0); LDB(BX, 0); STAGE_A(AY, 2 * it + 1, 0); \
        BARRIER(); MMA(0); BARRIER(); \
        LDA(AX, 0, 1); STAGE_B(BY, 2 * it + 1, 0); \
        BARRIER(); MMA(1); VM4(); BARRIER(); \
        LDA(AX, 1, 0); LDB(BX, 1); STAGE_A(AY, 2 * it + 1, 1); \
        BARRIER(); MMA(0); BARRIER(); \
        LDA(AX, 1, 1); STAGE_B(BY, 2 * it + 1, 1); \
        BARRIER(); MMA(1); VM4(); BARRIER(); \
        LDA(AY, 0, 0); LDB(BY, 0); if (!last) STAGE_A(AX, 2 * it + 2, 0); \
        BARRIER(); MMA(0); BARRIER(); \
        LDA(AY, 0, 1); if (!last) STAGE_B(BX, 2 * it + 2, 0); \
        BARRIER(); MMA(1); \
        if (!last) { VM4(); } else { VM0(); } \
        BARRIER(); \
        LDA(AY, 1, 0); LDB(BY, 1); if (!last) STAGE_A(AX, 2 * it + 2, 1); \
        BARRIER(); MMA(0); BARRIER(); \
        LDA(AY, 1, 1); if (!last) STAGE_B(BX, 2 * it + 2, 1); \
        BARRIER(); MMA(1); if (!last) VM4(); BARRIER(); \
    }

// ---------------------------------------------------------------------------
// Fused Q/K/V projection, 8-phase core. grid 768: XCD-swizzled;
// kind (0=Q,1=K,2=V), n0 = 0/256, m0 = tile row. (unchanged from round 4)
// ---------------------------------------------------------------------------
__global__ __launch_bounds__(512, 2) void gemm_qkv(
    const u16* __restrict__ qn, const u16* __restrict__ kvn,
    const u16* __restrict__ wq, const u16* __restrict__ wk, const u16* __restrict__ wv,
    const float* __restrict__ bq, const float* __restrict__ bk, const float* __restrict__ bv,
    const float* __restrict__ rope,
    u16* __restrict__ Qr, u16* __restrict__ Kr, u16* __restrict__ VT)
{
    __shared__ __align__(16) u16 smem[65536];  // 128 KB

    const int bid = blockIdx.x;
    const int swz = (bid & 7) * 96 + (bid >> 3);  // 768 % 8 == 0 -> bijective
    const int kind = swz >> 8;
    const int rem = swz & 255;
    const int n0 = (rem >> 7) << 8;   // 0 or 256
    const int m0 = (rem & 127) << 8;  // 0..32512

    const u16* Asrc = (kind == 0) ? qn : kvn;
    const u16* W = (kind == 0) ? wq : (kind == 1) ? wk : wv;
    const float* bias = (kind == 0) ? bq : (kind == 1) ? bk : bv;

    const int tid = threadIdx.x;
    const int lane = tid & 63, wid = tid >> 6;
    const int ln = lane & 15, lq = lane >> 4;
    const int wr = wid >> 2, wc = wid & 3;  // wave -> (2M x 4N) sub-tile

    const int rr = tid >> 2;
    const int cc = (tid & 3) ^ ((tid >> 3) & 3);
    const u16* aSt = Asrc + (size_t)(m0 + rr) * 512 + cc * 8;
    const u16* bSt = W + (size_t)(n0 + rr) * 512 + cc * 8;

    const int AX = 0, BX = 16384, AY = 32768, BY = 49152;
    const int swzc = lq ^ ((ln >> 1) & 3);
    const int aOff = wr * 4096 + ln * 32 + swzc * 8;
    const int bOff = wc * 2048 + ln * 32 + swzc * 8;

    f32x4 acc[8][4] = {};

    MAIN_LOOP_8PHASE();

    // ------------------------- epilogue -------------------------
    float bj[4];
#pragma unroll
    for (int j = 0; j < 4; ++j) bj[j] = bias[n0 + wc * 64 + j * 16 + ln];

    u16* sU = smem;  // 64 x 264 u16 staging (33 KB), reused per group

    if (kind < 2) {
        u16* Out = (kind == 0) ? Qr : Kr;
#pragma unroll
        for (int g = 0; g < 4; ++g) {  // row-groups of 64 tokens
            __syncthreads();
            if (wr == (g >> 1)) {
                const int i0 = (g & 1) * 4;
#pragma unroll
                for (int di = 0; di < 4; ++di)
#pragma unroll
                    for (int j = 0; j < 4; ++j)
#pragma unroll
                        for (int r = 0; r < 4; ++r)
                            sU[(di * 16 + lq * 4 + r) * 264 + wc * 64 + j * 16 + ln] =
                                f2bf(acc[i0 + di][j][r] + bj[j]);
            }
            __syncthreads();
#pragma unroll
            for (int it = 0; it < 4; ++it) {
                int idx = it * 512 + tid;
                int row = idx >> 5;
                int cseg = (idx & 31) << 3;
                u16x8 v = *(const u16x8*)&sU[row * 264 + cseg];
                int t = m0 + g * 64 + row;  // permuted row id (incl. batch)
                int n = swapb(t & 4095);    // original token for RoPE
                float f[8];
#pragma unroll
                for (int k = 0; k < 8; k++) f[k] = bf2f(v[k]);
                {
                    int d0 = cseg & 63;
                    const float* rp = &rope[n * 64 + d0];
                    f32x4 r0 = *(const f32x4*)rp;
                    f32x4 r1 = *(const f32x4*)(rp + 4);
#pragma unroll
                    for (int pp = 0; pp < 4; pp++) {
                        float sn = (pp < 2) ? r0[2 * pp] : r1[2 * (pp - 2)];
                        float cs2 = (pp < 2) ? r0[2 * pp + 1] : r1[2 * (pp - 2) + 1];
                        float x0 = f[2 * pp], x1 = f[2 * pp + 1];
                        f[2 * pp] = x0 * cs2 - x1 * sn;
                        f[2 * pp + 1] = x0 * sn + x1 * cs2;
                    }
                }
                u16x8 o;
#pragma unroll
                for (int k = 0; k < 8; k++) o[k] = f2bf(f[k]);
                *(u16x8*)&Out[(size_t)t * 512 + n0 + cseg] = o;
            }
        }
    } else {
        const int wq0 = m0 & 4095;
        const int bb = m0 >> 12;
#pragma unroll
        for (int g = 0; g < 4; ++g) {  // channel-groups of 64
            __syncthreads();
            if (wc == g) {  // 2 waves (wr 0,1) write their full acc transposed
#pragma unroll
                for (int i = 0; i < 8; ++i)
#pragma unroll
                    for (int j = 0; j < 4; ++j) {
                        u16x4 pk;
#pragma unroll
                        for (int r = 0; r < 4; ++r) pk[r] = f2bf(acc[i][j][r] + bj[j]);
                        *(u16x4*)&sU[(j * 16 + ln) * 264 + wr * 128 + i * 16 + lq * 4] = pk;
                    }
            }
            __syncthreads();
#pragma unroll
            for (int it = 0; it < 4; ++it) {
                int idx = it * 512 + tid;
                int col = idx >> 5;          // channel within group
                int ch = (idx & 31) << 3;    // token chunk
                u16x8 v = *(const u16x8*)&sU[col * 264 + ch];
                int c = n0 + g * 64 + col;
                int hh = c >> 6, dd = c & 63;
                *(u16x8*)&VT[((size_t)((((bb << 3) + hh) << 6) + dd)) * 4096 + wq0 + ch] = v;
            }
        }
    }
}

// ---------------------------------------------------------------------------
// Output projection, 8-phase 256^2 core. grid 256, XCD-swizzled.
// Epilogue: per 64-col group, stage residual + deposit acc+bias+res into
// 256x65 f32 LDS, then store swapb-runs of 32 contiguous tokens (128B lines).
// ---------------------------------------------------------------------------
__global__ __launch_bounds__(512, 2) void gemm_out(
    const u16* __restrict__ A, const u16* __restrict__ Bw,
    const float* __restrict__ bias, const u16* __restrict__ qn,
    float* __restrict__ Out)
{
    __shared__ __align__(16) u16 smem[65536];  // 128 KB

    const int bid = blockIdx.x;
    const int swz = (bid & 7) * 32 + (bid >> 3);  // 256 % 8 == 0 -> bijective
    const int n0 = (swz >> 7) << 8;   // 0 or 256
    const int m0 = (swz & 127) << 8;  // 0..32512

    const int tid = threadIdx.x;
    const int lane = tid & 63, wid = tid >> 6;
    const int ln = lane & 15, lq = lane >> 4;
    const int wr = wid >> 2, wc = wid & 3;

    const int rr = tid >> 2;
    const int cc = (tid & 3) ^ ((tid >> 3) & 3);
    const u16* aSt = A + (size_t)(m0 + rr) * 512 + cc * 8;
    const u16* bSt = Bw + (size_t)(n0 + rr) * 512 + cc * 8;

    const int AX = 0, BX = 16384, AY = 32768, BY = 49152;
    const int swzc = lq ^ ((ln >> 1) & 3);
    const int aOff = wr * 4096 + ln * 32 + swzc * 8;
    const int bOff = wc * 2048 + ln * 32 + swzc * 8;

    f32x4 acc[8][4] = {};

    MAIN_LOOP_8PHASE();

    // ------------------------- epilogue -------------------------
    // Within this 256-row tile (m0 multiple of 256), for any fixed channel the
    // un-permuted tokens nb = swapb(m0l + i) form 8 runs (r3 = i[5:3]) of 32
    // contiguous tokens: run base = swapb(m0l) + r3*64, offset o = i[7:6]<<3 | i[2:0].
    // Inverse used by the store: i = (o&4) + (o&3) + r3*8 + (o>>3)*64
    //   with o = op*4 + r  ->  i = ((op&1)<<2 | r) + r3*8 + (op>>1)*64.
    float bj[4];
#pragma unroll
    for (int j = 0; j < 4; ++j) bj[j] = bias[n0 + wc * 64 + j * 16 + ln];

    float* sOutF = (float*)smem;            // 256 x 65 f32 (66,560 B)
    u16* sRes = smem + 33280;               // byte 66,560: 256 x 72 u16 (36,864 B)
    const int bb = m0 >> 12;
    const int swb = swapb(m0 & 4095);
    const size_t outBase = ((size_t)((bb << 9) + n0)) << 12;

#pragma unroll
    for (int cg = 0; cg < 4; ++cg) {
        __syncthreads();
        // stage residual 256 rows x 64 cols (coalesced u16x8)
#pragma unroll
        for (int itq = 0; itq < 4; ++itq) {
            int idx = itq * 512 + tid;
            int row = idx >> 3, c8 = (idx & 7) << 3;
            *(u16x8*)&sRes[row * 72 + c8] =
                *(const u16x8*)&qn[(size_t)(m0 + row) * 512 + n0 + cg * 64 + c8];
        }
        __syncthreads();
        if (wc == cg) {  // 2 waves (wr 0,1) deposit acc + bias + residual
#pragma unroll
            for (int i = 0; i < 8; ++i)
#pragma unroll
                for (int j = 0; j < 4; ++j)
#pragma unroll
                    for (int r = 0; r < 4; ++r) {
                        int row = wr * 128 + i * 16 + lq * 4 + r;
                        int c = j * 16 + ln;
                        sOutF[row * 65 + c] =
                            acc[i][j][r] + bj[j] + bf2f(sRes[row * 72 + c]);
                    }
        }
        __syncthreads();
        // coalesced store: per wave, one channel per li; 8 lanes cover one 128B run
#pragma unroll
        for (int li = 0; li < 8; ++li) {
            int u = li * 512 + tid;
            int c = u >> 6, r3 = (u >> 3) & 7, op = u & 7;
            int base_i = ((op & 1) << 2) + (r3 << 3) + ((op >> 1) << 6);
            f32x4 v;
#pragma unroll
            for (int r = 0; r < 4; ++r) v[r] = sOutF[(base_i + r) * 65 + c];
            *(f32x4*)&Out[outBase + ((size_t)(cg * 64 + c) << 12) + swb + r3 * 64 + op * 4] = v;
        }
    }
}

#undef SB
#undef BARRIER
#undef VM4
#undef VM0
#undef STAGE_A
#undef STAGE_B
#undef LDA
#undef LDB
#undef MMA
#undef MAIN_LOOP_8PHASE

// ---------------------------------------------------------------------------
// Windowed attention tile: QK^T + bias + softmax + PV for one (b,w,h) 64x64 tile.
// Layouts identical to previous rounds; sPp is the wave's private P strip.
// ---------------------------------------------------------------------------
__device__ __forceinline__ void attn_tile(
    const u16* __restrict__ sQp, const u16* __restrict__ sKp,
    const u16* __restrict__ sVTp, u16* __restrict__ sPp,
    const float* __restrict__ biasf, int h, int wave, int ln, int lq, f32x4 o[4])
{
    f32x4 s[4] = {};
#pragma unroll
    for (int ks = 0; ks < 2; ks++) {
        bf16x8 a = *(const bf16x8*)&sQp[(wave * 16 + ln) * 72 + ks * 32 + lq * 8];
#pragma unroll
        for (int j = 0; j < 4; j++) {
            bf16x8 bb = *(const bf16x8*)&sKp[(j * 16 + ln) * 72 + ks * 32 + lq * 8];
            s[j] = mfma16(a, bb, s[j]);
        }
    }

    float sv[4][4];
#pragma unroll
    for (int r = 0; r < 4; r++) {
        const float* bp = &biasf[((h * 64 + wave * 16 + lq * 4 + r) << 6) + ln];
#pragma unroll
        for (int j = 0; j < 4; j++) sv[r][j] = s[j][r] * 0.125f + bp[j * 16];
    }
#pragma unroll
    for (int r = 0; r < 4; r++) {
        float m = fmaxf(fmaxf(sv[r][0], sv[r][1]), fmaxf(sv[r][2], sv[r][3]));
        m = fmaxf(m, __shfl_xor(m, 1));
        m = fmaxf(m, __shfl_xor(m, 2));
        m = fmaxf(m, __shfl_xor(m, 4));
        m = fmaxf(m, __shfl_xor(m, 8));
        float sum = 0.f;
#pragma unroll
        for (int j = 0; j < 4; j++) {
            sv[r][j] = __expf(sv[r][j] - m);
            sum += sv[r][j];
        }
        sum += __shfl_xor(sum, 1);
        sum += __shfl_xor(sum, 2);
        sum += __shfl_xor(sum, 4);
        sum += __shfl_xor(sum, 8);
        float rinv = 1.f / sum;
#pragma unroll
        for (int j = 0; j < 4; j++)
            sPp[(lq * 4 + r) * 72 + j * 16 + ln] = f2bf(sv[r][j] * rinv);
    }
    // wave-private strip: no barrier needed

    o[0] = f32x4{0.f, 0.f, 0.f, 0.f};
    o[1] = f32x4{0.f, 0.f, 0.f, 0.f};
    o[2] = f32x4{0.f, 0.f, 0.f, 0.f};
    o[3] = f32x4{0.f, 0.f, 0.f, 0.f};
#pragma unroll
    for (int ks = 0; ks < 2; ks++) {
        bf16x8 a = *(const bf16x8*)&sPp[ln * 72 + ks * 32 + lq * 8];
#pragma unroll
        for (int jd = 0; jd < 4; jd++) {
            bf16x8 bb = *(const bf16x8*)&sVTp[(jd * 16 + ln) * 72 + ks * 32 + lq * 8];
            o[jd] = mfma16(a, bb, o[jd]);
        }
    }
}

// ---------------------------------------------------------------------------
// Windowed attention: block = (b, window, head-pair); grid 2048 x 256.
// Both tiles' global loads issued up-front (reg-staged); tile-1 loads stay in
// flight under tile-0 compute. Per-tile math identical to previous rounds.
// ---------------------------------------------------------------------------
__global__ __launch_bounds__(256) void attn_kernel(
    const u16* __restrict__ Q, const u16* __restrict__ K, const u16* __restrict__ VT,
    const float* __restrict__ biasf, u16* __restrict__ Out)
{
    __shared__ u16 sQ[2][64 * 72];   // each reused as output staging
    __shared__ u16 sK[2][64 * 72];
    __shared__ u16 sVT[2][64 * 72];  // [d][token]
    __shared__ u16 sP[2][4][16 * 72];

    const int tid = threadIdx.x;
    const int code0 = blockIdx.x << 1;       // head-pair: h0 even, h1 = h0+1
    const int h0 = code0 & 7;
    const int w = (code0 >> 3) & 63;
    const int b = code0 >> 9;
    const int lane = tid & 63, wave = tid >> 6;
    const int ln = lane & 15, lq = lane >> 4;

    const size_t qrow0 = (size_t)(b << 12) + w * 64;

    // issue ALL global loads (both tiles) up-front; T1 flies under T0 compute
    u16x8 rq[2][2], rk[2][2], rv[2][2];
#pragma unroll
    for (int t = 0; t < 2; ++t) {
        const int h = h0 + t;
        const size_t vrow0 = ((size_t)(((b << 3) + h) << 6)) * 4096 + w * 64;
#pragma unroll
        for (int ii = 0; ii < 2; ii++) {
            int idx = ii * 256 + tid;
            int rw = idx >> 3, ch = (idx & 7) << 3;
            size_t ga = (qrow0 + rw) * 512 + h * 64 + ch;
            rq[t][ii] = *(const u16x8*)&Q[ga];
            rk[t][ii] = *(const u16x8*)&K[ga];
            rv[t][ii] = *(const u16x8*)&VT[vrow0 + (size_t)rw * 4096 + ch];
        }
    }
#pragma unroll
    for (int ii = 0; ii < 2; ii++) {
        int idx = ii * 256 + tid;
        int rw = idx >> 3, ch = (idx & 7) << 3;
        *(u16x8*)&sQ[0][rw * 72 + ch] = rq[0][ii];
        *(u16x8*)&sK[0][rw * 72 + ch] = rk[0][ii];
        *(u16x8*)&sVT[0][rw * 72 + ch] = rv[0][ii];
    }
    __syncthreads();

    f32x4 o[4];
    attn_tile(sQ[0], sK[0], sVT[0], sP[0][wave], biasf, h0, wave, ln, lq, o);

    // write tile-1 LDS (loads landed during T0 compute)
#pragma unroll
    for (int ii = 0; ii < 2; ii++) {
        int idx = ii * 256 + tid;
        int rw = idx >> 3, ch = (idx & 7) << 3;
        *(u16x8*)&sQ[1][rw * 72 + ch] = rq[1][ii];
        *(u16x8*)&sK[1][rw * 72 + ch] = rk[1][ii];
        *(u16x8*)&sVT[1][rw * 72 + ch] = rv[1][ii];
    }
    // stage T0 output into sQ[0] (wave-local rows; wave's Q reads are done)
#pragma unroll
    for (int r = 0; r < 4; r++)
#pragma unroll
        for (int jd = 0; jd < 4; jd++)
            sQ[0][(wave * 16 + lq * 4 + r) * 72 + jd * 16 + ln] = f2bf(o[jd][r]);
    __syncthreads();

    // store T0 + compute T1
#pragma unroll
    for (int ii = 0; ii < 2; ii++) {
        int idx = ii * 256 + tid;
        int rw = idx >> 3, ch = (idx & 7) << 3;
        *(u16x8*)&Out[(qrow0 + rw) * 512 + h0 * 64 + ch] = *(const u16x8*)&sQ[0][rw * 72 + ch];
    }
    attn_tile(sQ[1], sK[1], sVT[1], sP[1][wave], biasf, h0 + 1, wave, ln, lq, o);
#pragma unroll
    for (int r = 0; r < 4; r++)
#pragma unroll
        for (int jd = 0; jd < 4; jd++)
            sQ[1][(wave * 16 + lq * 4 + r) * 72 + jd * 16 + ln] = f2bf(o[jd][r]);
    __syncthreads();
#pragma unroll
    for (int ii = 0; ii < 2; ii++) {
        int idx = ii * 256 + tid;
        int rw = idx >> 3, ch = (idx & 7) << 3;
        *(u16x8*)&Out[(qrow0 + rw) * 512 + (h0 + 1) * 64 + ch] =
            *(const u16x8*)&sQ[1][rw * 72 + ch];
    }
}

// ---------------------------------------------------------------------------
extern "C" void kernel_launch(void* const* d_in, const int* in_sizes, int n_in,
                              void* d_out, int out_size, void* d_ws, size_t ws_size,
                              hipStream_t stream)
{
    const float* q    = (const float*)d_in[0];
    const float* kv   = (const float*)d_in[1];
    const float* g_q  = (const float*)d_in[2];
    const float* b_q  = (const float*)d_in[3];
    const float* g_kv = (const float*)d_in[4];
    const float* b_kv = (const float*)d_in[5];
    const float* Wq   = (const float*)d_in[6];
    const float* bq   = (const float*)d_in[7];
    const float* Wk   = (const float*)d_in[8];
    const float* bk   = (const float*)d_in[9];
    const float* Wv   = (const float*)d_in[10];
    const float* bv   = (const float*)d_in[11];
    const float* Wo   = (const float*)d_in[12];
    const float* bo   = (const float*)d_in[13];
    const float* btab = (const float*)d_in[14];

    char* ws = (char*)d_ws;
    u16* qn      = (u16*)(ws);                 // 33,554,432 B  (permuted token order)
    u16* kvn     = (u16*)(ws + 33554432);      // 33,554,432 B  (reused as attn out)
    u16* VT      = (u16*)(ws + 67108864);      // 33,554,432 B  (b,h,d,wpos)
    float* rope  = (float*)(ws + 100663296);   // 1,048,576 B
    float* biasf = (float*)(ws + 101711872);   // 131,072 B
    u16* wq      = (u16*)(ws + 101842944);     // 4 x 524,288 B
    u16* wk      = (u16*)(ws + 102367232);
    u16* wv      = (u16*)(ws + 102891520);
    u16* wo      = (u16*)(ws + 103415808);
    u16* aout    = kvn;                        // safe: kvn consumed by QKV projection
    u16* Qr      = (u16*)d_out;                // d_out as scratch for Q/K (bf16)
    u16* Kr      = Qr + 16777216;

    prep_kernel<<<6144, 256, 0, stream>>>(q, kv, g_q, b_q, g_kv, b_kv,
                                          Wq, Wk, Wv, Wo, btab,
                                          qn, kvn, wq, wk, wv, wo, rope, biasf);
    gemm_qkv<<<768, 512, 0, stream>>>(qn, kvn, wq, wk, wv, bq, bk, bv, rope, Qr, Kr, VT);
    attn_kernel<<<2048, 256, 0, stream>>>(Qr, Kr, VT, biasf, aout);
    gemm_out<<<256, 512, 0, stream>>>(aout, wo, bo, qn, (float*)d_out);
}

// Round 8
// 349.963 us; speedup vs baseline: 1.0872x; 1.0872x over previous
//
#include <hip/hip_runtime.h>

// Problem: B=8, C=512, H=W=64, NH=8, D=64, window 8x8 (Ws=64), N=4096.
// Token dim is window-permuted AT THE LAYERNORM (bit-swap n[8:6]<->n[5:3], involution):
// qn/kvn/Q/K/V/attn-out all live in permuted space (windows contiguous); un-permute
// happens only in gemm_out's final transposed store. V stored transposed (b,h,d,wpos).
//
// Round-8: A/A calibration. Round-7's control (gemm_qkv, byte-identical to r4/r5)
// slowed 80->113us with hbm_gbps down exactly 1.41x -> cross-session clock/node
// variance. gemm_qkv/attn/gemm_out kept byte-identical. Only prep changed (isolated):
// setup role vectorized (u16x4 weight stores, f32x2 rope stores; grid 6144->3712),
// LN input unroll 4->8.

typedef unsigned short u16;
typedef __bf16 bf16x8 __attribute__((ext_vector_type(8)));
typedef float f32x4 __attribute__((ext_vector_type(4)));
typedef float f32x2 __attribute__((ext_vector_type(2)));
typedef u16 u16x8 __attribute__((ext_vector_type(8)));
typedef u16 u16x4 __attribute__((ext_vector_type(4)));

__device__ __forceinline__ u16 f2bf(float f) {
    __bf16 h = (__bf16)f;
    return __builtin_bit_cast(u16, h);
}
__device__ __forceinline__ float bf2f(u16 u) {
    return (float)__builtin_bit_cast(__bf16, u);
}
__device__ __forceinline__ f32x4 mfma16(bf16x8 a, bf16x8 b, f32x4 c) {
    return __builtin_amdgcn_mfma_f32_16x16x32_bf16(a, b, c, 0, 0, 0);
}
__device__ __forceinline__ void gl_lds16(const u16* g, u16* l) {
    __builtin_amdgcn_global_load_lds((const __attribute__((address_space(1))) void*)g,
                                     (__attribute__((address_space(3))) void*)l, 16, 0, 0);
}
// window permutation: n = hn[11:9] r[8:6] wn[5:3] cc[2:0] -> hn wn r cc  (involution)
__device__ __forceinline__ int swapb(int n) {
    return (n & 0xE07) | ((n & 0x1C0) >> 3) | ((n & 0x038) << 3);
}

// ---------------------------------------------------------------------------
// prep_kernel: grid 3712 x 256.
//  blocks [0,1024):    LayerNorm q  -> qn   (permuted bf16)
//  blocks [1024,2048): LayerNorm kv -> kvn
//  blocks [2048,3072): weights f32->bf16, u16x4-vectorized (4 elems/thread)
//  blocks [3072,3584): RoPE table (1 sin/cos pair per thread, f32x2 store)
//  blocks [3584,3712): bias table
// ---------------------------------------------------------------------------
__global__ __launch_bounds__(256) void prep_kernel(
    const float* __restrict__ q, const float* __restrict__ kv,
    const float* __restrict__ g_q, const float* __restrict__ b_q,
    const float* __restrict__ g_kv, const float* __restrict__ b_kv,
    const float* __restrict__ Wq, const float* __restrict__ Wk,
    const float* __restrict__ Wv, const float* __restrict__ Wo,
    const float* __restrict__ btab,
    u16* __restrict__ qn, u16* __restrict__ kvn,
    u16* __restrict__ wq, u16* __restrict__ wk,
    u16* __restrict__ wv, u16* __restrict__ wo,
    float* __restrict__ rope, float* __restrict__ biasf)
{
    __shared__ u16 sX[512 * 36];  // [c][token], stride 36 (8B-aligned u16x4 stores)
    __shared__ float sS[1024];
    __shared__ float sQm[1024];
    __shared__ float sMu[32], sInv[32];

    const int bidx = blockIdx.x;
    const int tid = threadIdx.x;

    if (bidx >= 2048) {  // ---------------- setup roles ----------------
        if (bidx < 3072) {  // weights: 4 elems/thread, vectorized
            int idx = (bidx - 2048) * 256 + tid;       // [0, 262144)
            int w = idx >> 16, qd = idx & 65535;       // matrix, quad index
            const float* src = (w == 0) ? Wq : (w == 1) ? Wk : (w == 2) ? Wv : Wo;
            u16* dst = (w == 0) ? wq : (w == 1) ? wk : (w == 2) ? wv : wo;
            f32x4 v = *(const f32x4*)&src[qd * 4];
            u16x4 h;
#pragma unroll
            for (int r = 0; r < 4; r++) h[r] = f2bf(v[r]);
            *(u16x4*)&dst[qd * 4] = h;
        } else if (bidx < 3584) {  // rope
            int idx = (bidx - 3072) * 256 + tid;       // [0, 131072)
            int n = idx >> 5, j = idx & 31;
            float inv = powf(10000.0f, -(float)j / 32.0f);
            float a = (float)n * inv;
            float s, c;
            sincosf(a, &s, &c);
            f32x2 sc;
            sc[0] = s;
            sc[1] = c;
            *(f32x2*)&rope[n * 64 + 2 * j] = sc;
        } else {  // bias
            int idx = (bidx - 3584) * 256 + tid;       // [0, 32768)
            int qq = idx & 63, pp = (idx >> 6) & 63, h = idx >> 12;
            int r1 = pp >> 3, c1 = pp & 7, r2 = qq >> 3, c2 = qq & 7;
            int ri = (r1 - r2 + 7) * 15 + (c1 - c2 + 7);
            biasf[idx] = btab[ri * 8 + h];
        }
        return;
    }

    // ---------------- LayerNorm role ----------------
    const float* x  = (bidx < 1024) ? q : kv;
    const float* g  = (bidx < 1024) ? g_q : g_kv;
    const float* be = (bidx < 1024) ? b_q : b_kv;
    u16* out = (bidx < 1024) ? qn : kvn;
    const int bid = bidx & 1023;

    const int b = bid >> 7, grp = bid & 127;
    const int nbase = grp << 5;
    const int t4 = tid & 7;   // token quad (4 tokens each)
    const int cg = tid >> 3;  // 32 channels per iteration

    const float* xp = x + ((size_t)b << 21) + nbase + (t4 << 2);
    float sm[4] = {0.f, 0.f, 0.f, 0.f}, sq2[4] = {0.f, 0.f, 0.f, 0.f};
#pragma unroll 8
    for (int it = 0; it < 16; it++) {
        int c = (it << 5) + cg;
        f32x4 v = *(const f32x4*)&xp[(size_t)c << 12];
        u16x4 h;
#pragma unroll
        for (int r = 0; r < 4; r++) {
            sm[r] += v[r];
            sq2[r] += v[r] * v[r];
            h[r] = f2bf(v[r]);
        }
        *(u16x4*)&sX[c * 36 + (t4 << 2)] = h;
    }
#pragma unroll
    for (int r = 0; r < 4; r++) {
        sS[tid * 4 + r] = sm[r];
        sQm[tid * 4 + r] = sq2[r];
    }
    __syncthreads();
    if (tid < 32) {  // token tid: t4v = tid>>2, r = tid&3
        int t4v = tid >> 2, r = tid & 3;
        float a = 0.f, q2 = 0.f;
#pragma unroll
        for (int c2 = 0; c2 < 32; c2++) {
            int i2 = ((c2 << 3) + t4v) * 4 + r;
            a += sS[i2];
            q2 += sQm[i2];
        }
        float mu = a * (1.f / 512.f);
        float var = q2 * (1.f / 512.f) - mu * mu;
        sMu[tid] = mu;
        sInv[tid] = rsqrtf(var + 1e-5f);
    }
    __syncthreads();

    const int t = tid >> 3;         // 0..31
    const int cs = (tid & 7) << 3;  // 0..56
    float mu = sMu[t], inv = sInv[t];
    int p = swapb(nbase + t);  // permuted row
    size_t orow = ((size_t)((b << 12) + p)) * 512;
#pragma unroll
    for (int it = 0; it < 8; it++) {
        int c0 = cs + (it << 6);
        f32x4 g0 = *(const f32x4*)&g[c0];
        f32x4 g1 = *(const f32x4*)&g[c0 + 4];
        f32x4 e0 = *(const f32x4*)&be[c0];
        f32x4 e1 = *(const f32x4*)&be[c0 + 4];
        u16x8 o;
#pragma unroll
        for (int k = 0; k < 8; k++) {
            float v = bf2f(sX[(c0 + k) * 36 + t]);
            float gg = (k < 4) ? g0[k] : g1[k - 4];
            float bb = (k < 4) ? e0[k] : e1[k - 4];
            o[k] = f2bf((v - mu) * inv * gg + bb);
        }
        *(u16x8*)&out[orow + c0] = o;
    }
}

// ---------------------------------------------------------------------------
// Shared 8-phase 256x256 / BK=64 / 8-wave main-loop machinery (round-4 verified).
// ---------------------------------------------------------------------------
#define SB() __builtin_amdgcn_sched_barrier(0)
#define BARRIER() do { SB(); __builtin_amdgcn_s_barrier(); SB(); } while (0)
#define VM4() asm volatile("s_waitcnt vmcnt(4)" ::: "memory")
#define VM0() asm volatile("s_waitcnt vmcnt(0)" ::: "memory")
#define STAGE_A(base, kt, kk) do { \
        const u16* _g = aSt + (kt) * 64 + (kk) * 32; \
        gl_lds16(_g, &smem[(base) + (kk) * 8192 + wid * 512]); \
        gl_lds16(_g + 65536, &smem[(base) + (kk) * 8192 + 4096 + wid * 512]); \
    } while (0)
#define STAGE_B(base, kt, kk) do { \
        const u16* _g = bSt + (kt) * 64 + (kk) * 32; \
        gl_lds16(_g, &smem[(base) + (kk) * 8192 + wid * 512]); \
        gl_lds16(_g + 65536, &smem[(base) + (kk) * 8192 + 4096 + wid * 512]); \
    } while (0)
#define LDA(base, kk, mh) do { \
        Af[0] = *(const bf16x8*)&smem[(base) + (kk) * 8192 + (mh) * 2048 + 0 * 512 + aOff]; \
        Af[1] = *(const bf16x8*)&smem[(base) + (kk) * 8192 + (mh) * 2048 + 1 * 512 + aOff]; \
        Af[2] = *(const bf16x8*)&smem[(base) + (kk) * 8192 + (mh) * 2048 + 2 * 512 + aOff]; \
        Af[3] = *(const bf16x8*)&smem[(base) + (kk) * 8192 + (mh) * 2048 + 3 * 512 + aOff]; \
    } while (0)
#define LDB(base, kk) do { \
        Bf[0] = *(const bf16x8*)&smem[(base) + (kk) * 8192 + 0 * 512 + bOff]; \
        Bf[1] = *(const bf16x8*)&smem[(base) + (kk) * 8192 + 1 * 512 + bOff]; \
        Bf[2] = *(const bf16x8*)&smem[(base) + (kk) * 8192 + 2 * 512 + bOff]; \
        Bf[3] = *(const bf16x8*)&smem[(base) + (kk) * 8192 + 3 * 512 + bOff]; \
    } while (0)
#define MMA(mh) do { \
        __builtin_amdgcn_s_setprio(1); \
        _Pragma("unroll") \
        for (int fi = 0; fi < 4; ++fi) \
            _Pragma("unroll") \
            for (int j = 0; j < 4; ++j) \
                acc[(mh) * 4 + fi][j] = mfma16(Af[fi], Bf[j], acc[(mh) * 4 + fi][j]); \
        __builtin_amdgcn_s_setprio(0); \
    } while (0)

#define MAIN_LOOP_8PHASE() \
    STAGE_A(AX, 0, 0); \
    STAGE_B(BX, 0, 0); \
    STAGE_A(AX, 0, 1); \
    STAGE_B(BX, 0, 1); \
    VM4(); \
    BARRIER(); \
    _Pragma("unroll") \
    for (int it = 0; it < 4; ++it) { \
        const bool last = (it == 3); \
        bf16x8 Af[4], Bf[4]; \
        LDA(AX, 0, 0); LDB(BX, 0); STAGE_A(AY, 2 * it + 1, 0); \
        BARRIER(); MMA(0); BARRIER(); \
        LDA(AX, 0, 1); STAGE_B(BY, 2 * it + 1, 0); \
        BARRIER(); MMA(1); VM4(); BARRIER(); \
        LDA(AX, 1, 0); LDB(BX, 1); STAGE_A(AY, 2 * it + 1, 1); \
        BARRIER(); MMA(0); BARRIER(); \
        LDA(AX, 1, 1); STAGE_B(BY, 2 * it + 1, 1); \
        BARRIER(); MMA(1); VM4(); BARRIER(); \
        LDA(AY, 0, 0); LDB(BY, 0); if (!last) STAGE_A(AX, 2 * it + 2, 0); \
        BARRIER(); MMA(0); BARRIER(); \
        LDA(AY, 0, 1); if (!last) STAGE_B(BX, 2 * it + 2, 0); \
        BARRIER(); MMA(1); \
        if (!last) { VM4(); } else { VM0(); } \
        BARRIER(); \
        LDA(AY, 1, 0); LDB(BY, 1); if (!last) STAGE_A(AX, 2 * it + 2, 1); \
        BARRIER(); MMA(0); BARRIER(); \
        LDA(AY, 1, 1); if (!last) STAGE_B(BX, 2 * it + 2, 1); \
        BARRIER(); MMA(1); if (!last) VM4(); BARRIER(); \
    }

// ---------------------------------------------------------------------------
// Fused Q/K/V projection, 8-phase core. grid 768: XCD-swizzled;
// kind (0=Q,1=K,2=V), n0 = 0/256, m0 = tile row. (unchanged from round 4)
// ---------------------------------------------------------------------------
__global__ __launch_bounds__(512, 2) void gemm_qkv(
    const u16* __restrict__ qn, const u16* __restrict__ kvn,
    const u16* __restrict__ wq, const u16* __restrict__ wk, const u16* __restrict__ wv,
    const float* __restrict__ bq, const float* __restrict__ bk, const float* __restrict__ bv,
    const float* __restrict__ rope,
    u16* __restrict__ Qr, u16* __restrict__ Kr, u16* __restrict__ VT)
{
    __shared__ __align__(16) u16 smem[65536];  // 128 KB

    const int bid = blockIdx.x;
    const int swz = (bid & 7) * 96 + (bid >> 3);  // 768 % 8 == 0 -> bijective
    const int kind = swz >> 8;
    const int rem = swz & 255;
    const int n0 = (rem >> 7) << 8;   // 0 or 256
    const int m0 = (rem & 127) << 8;  // 0..32512

    const u16* Asrc = (kind == 0) ? qn : kvn;
    const u16* W = (kind == 0) ? wq : (kind == 1) ? wk : wv;
    const float* bias = (kind == 0) ? bq : (kind == 1) ? bk : bv;

    const int tid = threadIdx.x;
    const int lane = tid & 63, wid = tid >> 6;
    const int ln = lane & 15, lq = lane >> 4;
    const int wr = wid >> 2, wc = wid & 3;  // wave -> (2M x 4N) sub-tile

    const int rr = tid >> 2;
    const int cc = (tid & 3) ^ ((tid >> 3) & 3);
    const u16* aSt = Asrc + (size_t)(m0 + rr) * 512 + cc * 8;
    const u16* bSt = W + (size_t)(n0 + rr) * 512 + cc * 8;

    const int AX = 0, BX = 16384, AY = 32768, BY = 49152;
    const int swzc = lq ^ ((ln >> 1) & 3);
    const int aOff = wr * 4096 + ln * 32 + swzc * 8;
    const int bOff = wc * 2048 + ln * 32 + swzc * 8;

    f32x4 acc[8][4] = {};

    MAIN_LOOP_8PHASE();

    // ------------------------- epilogue -------------------------
    float bj[4];
#pragma unroll
    for (int j = 0; j < 4; ++j) bj[j] = bias[n0 + wc * 64 + j * 16 + ln];

    u16* sU = smem;  // 64 x 264 u16 staging (33 KB), reused per group

    if (kind < 2) {
        u16* Out = (kind == 0) ? Qr : Kr;
#pragma unroll
        for (int g = 0; g < 4; ++g) {  // row-groups of 64 tokens
            __syncthreads();
            if (wr == (g >> 1)) {
                const int i0 = (g & 1) * 4;
#pragma unroll
                for (int di = 0; di < 4; ++di)
#pragma unroll
                    for (int j = 0; j < 4; ++j)
#pragma unroll
                        for (int r = 0; r < 4; ++r)
                            sU[(di * 16 + lq * 4 + r) * 264 + wc * 64 + j * 16 + ln] =
                                f2bf(acc[i0 + di][j][r] + bj[j]);
            }
            __syncthreads();
#pragma unroll
            for (int it = 0; it < 4; ++it) {
                int idx = it * 512 + tid;
                int row = idx >> 5;
                int cseg = (idx & 31) << 3;
                u16x8 v = *(const u16x8*)&sU[row * 264 + cseg];
                int t = m0 + g * 64 + row;  // permuted row id (incl. batch)
                int n = swapb(t & 4095);    // original token for RoPE
                float f[8];
#pragma unroll
                for (int k = 0; k < 8; k++) f[k] = bf2f(v[k]);
                {
                    int d0 = cseg & 63;
                    const float* rp = &rope[n * 64 + d0];
                    f32x4 r0 = *(const f32x4*)rp;
                    f32x4 r1 = *(const f32x4*)(rp + 4);
#pragma unroll
                    for (int pp = 0; pp < 4; pp++) {
                        float sn = (pp < 2) ? r0[2 * pp] : r1[2 * (pp - 2)];
                        float cs2 = (pp < 2) ? r0[2 * pp + 1] : r1[2 * (pp - 2) + 1];
                        float x0 = f[2 * pp], x1 = f[2 * pp + 1];
                        f[2 * pp] = x0 * cs2 - x1 * sn;
                        f[2 * pp + 1] = x0 * sn + x1 * cs2;
                    }
                }
                u16x8 o;
#pragma unroll
                for (int k = 0; k < 8; k++) o[k] = f2bf(f[k]);
                *(u16x8*)&Out[(size_t)t * 512 + n0 + cseg] = o;
            }
        }
    } else {
        const int wq0 = m0 & 4095;
        const int bb = m0 >> 12;
#pragma unroll
        for (int g = 0; g < 4; ++g) {  // channel-groups of 64
            __syncthreads();
            if (wc == g) {  // 2 waves (wr 0,1) write their full acc transposed
#pragma unroll
                for (int i = 0; i < 8; ++i)
#pragma unroll
                    for (int j = 0; j < 4; ++j) {
                        u16x4 pk;
#pragma unroll
                        for (int r = 0; r < 4; ++r) pk[r] = f2bf(acc[i][j][r] + bj[j]);
                        *(u16x4*)&sU[(j * 16 + ln) * 264 + wr * 128 + i * 16 + lq * 4] = pk;
                    }
            }
            __syncthreads();
#pragma unroll
            for (int it = 0; it < 4; ++it) {
                int idx = it * 512 + tid;
                int col = idx >> 5;          // channel within group
                int ch = (idx & 31) << 3;    // token chunk
                u16x8 v = *(const u16x8*)&sU[col * 264 + ch];
                int c = n0 + g * 64 + col;
                int hh = c >> 6, dd = c & 63;
                *(u16x8*)&VT[((size_t)((((bb << 3) + hh) << 6) + dd)) * 4096 + wq0 + ch] = v;
            }
        }
    }
}

// ---------------------------------------------------------------------------
// Output projection, 8-phase 256^2 core. grid 256, XCD-swizzled.
// Epilogue: per 64-col group, stage residual + deposit acc+bias+res into
// 256x65 f32 LDS, then store swapb-runs of 32 contiguous tokens (128B lines).
// ---------------------------------------------------------------------------
__global__ __launch_bounds__(512, 2) void gemm_out(
    const u16* __restrict__ A, const u16* __restrict__ Bw,
    const float* __restrict__ bias, const u16* __restrict__ qn,
    float* __restrict__ Out)
{
    __shared__ __align__(16) u16 smem[65536];  // 128 KB

    const int bid = blockIdx.x;
    const int swz = (bid & 7) * 32 + (bid >> 3);  // 256 % 8 == 0 -> bijective
    const int n0 = (swz >> 7) << 8;   // 0 or 256
    const int m0 = (swz & 127) << 8;  // 0..32512

    const int tid = threadIdx.x;
    const int lane = tid & 63, wid = tid >> 6;
    const int ln = lane & 15, lq = lane >> 4;
    const int wr = wid >> 2, wc = wid & 3;

    const int rr = tid >> 2;
    const int cc = (tid & 3) ^ ((tid >> 3) & 3);
    const u16* aSt = A + (size_t)(m0 + rr) * 512 + cc * 8;
    const u16* bSt = Bw + (size_t)(n0 + rr) * 512 + cc * 8;

    const int AX = 0, BX = 16384, AY = 32768, BY = 49152;
    const int swzc = lq ^ ((ln >> 1) & 3);
    const int aOff = wr * 4096 + ln * 32 + swzc * 8;
    const int bOff = wc * 2048 + ln * 32 + swzc * 8;

    f32x4 acc[8][4] = {};

    MAIN_LOOP_8PHASE();

    // ------------------------- epilogue -------------------------
    // Within this 256-row tile (m0 multiple of 256), for any fixed channel the
    // un-permuted tokens nb = swapb(m0l + i) form 8 runs (r3 = i[5:3]) of 32
    // contiguous tokens: run base = swapb(m0l) + r3*64, offset o = i[7:6]<<3 | i[2:0].
    // Inverse used by the store: o = op*4 + r  ->  i = ((op&1)<<2 | r) + r3*8 + (op>>1)*64.
    float bj[4];
#pragma unroll
    for (int j = 0; j < 4; ++j) bj[j] = bias[n0 + wc * 64 + j * 16 + ln];

    float* sOutF = (float*)smem;            // 256 x 65 f32 (66,560 B)
    u16* sRes = smem + 33280;               // byte 66,560: 256 x 72 u16 (36,864 B)
    const int bb = m0 >> 12;
    const int swb = swapb(m0 & 4095);
    const size_t outBase = ((size_t)((bb << 9) + n0)) << 12;

#pragma unroll
    for (int cg = 0; cg < 4; ++cg) {
        __syncthreads();
        // stage residual 256 rows x 64 cols (coalesced u16x8)
#pragma unroll
        for (int itq = 0; itq < 4; ++itq) {
            int idx = itq * 512 + tid;
            int row = idx >> 3, c8 = (idx & 7) << 3;
            *(u16x8*)&sRes[row * 72 + c8] =
                *(const u16x8*)&qn[(size_t)(m0 + row) * 512 + n0 + cg * 64 + c8];
        }
        __syncthreads();
        if (wc == cg) {  // 2 waves (wr 0,1) deposit acc + bias + residual
#pragma unroll
            for (int i = 0; i < 8; ++i)
#pragma unroll
                for (int j = 0; j < 4; ++j)
#pragma unroll
                    for (int r = 0; r < 4; ++r) {
                        int row = wr * 128 + i * 16 + lq * 4 + r;
                        int c = j * 16 + ln;
                        sOutF[row * 65 + c] =
                            acc[i][j][r] + bj[j] + bf2f(sRes[row * 72 + c]);
                    }
        }
        __syncthreads();
        // coalesced store: per wave, one channel per li; 8 lanes cover one 128B run
#pragma unroll
        for (int li = 0; li < 8; ++li) {
            int u = li * 512 + tid;
            int c = u >> 6, r3 = (u >> 3) & 7, op = u & 7;
            int base_i = ((op & 1) << 2) + (r3 << 3) + ((op >> 1) << 6);
            f32x4 v;
#pragma unroll
            for (int r = 0; r < 4; ++r) v[r] = sOutF[(base_i + r) * 65 + c];
            *(f32x4*)&Out[outBase + ((size_t)(cg * 64 + c) << 12) + swb + r3 * 64 + op * 4] = v;
        }
    }
}

#undef SB
#undef BARRIER
#undef VM4
#undef VM0
#undef STAGE_A
#undef STAGE_B
#undef LDA
#undef LDB
#undef MMA
#undef MAIN_LOOP_8PHASE

// ---------------------------------------------------------------------------
// Windowed attention tile: QK^T + bias + softmax + PV for one (b,w,h) 64x64 tile.
// Layouts identical to previous rounds; sPp is the wave's private P strip.
// ---------------------------------------------------------------------------
__device__ __forceinline__ void attn_tile(
    const u16* __restrict__ sQp, const u16* __restrict__ sKp,
    const u16* __restrict__ sVTp, u16* __restrict__ sPp,
    const float* __restrict__ biasf, int h, int wave, int ln, int lq, f32x4 o[4])
{
    f32x4 s[4] = {};
#pragma unroll
    for (int ks = 0; ks < 2; ks++) {
        bf16x8 a = *(const bf16x8*)&sQp[(wave * 16 + ln) * 72 + ks * 32 + lq * 8];
#pragma unroll
        for (int j = 0; j < 4; j++) {
            bf16x8 bb = *(const bf16x8*)&sKp[(j * 16 + ln) * 72 + ks * 32 + lq * 8];
            s[j] = mfma16(a, bb, s[j]);
        }
    }

    float sv[4][4];
#pragma unroll
    for (int r = 0; r < 4; r++) {
        const float* bp = &biasf[((h * 64 + wave * 16 + lq * 4 + r) << 6) + ln];
#pragma unroll
        for (int j = 0; j < 4; j++) sv[r][j] = s[j][r] * 0.125f + bp[j * 16];
    }
#pragma unroll
    for (int r = 0; r < 4; r++) {
        float m = fmaxf(fmaxf(sv[r][0], sv[r][1]), fmaxf(sv[r][2], sv[r][3]));
        m = fmaxf(m, __shfl_xor(m, 1));
        m = fmaxf(m, __shfl_xor(m, 2));
        m = fmaxf(m, __shfl_xor(m, 4));
        m = fmaxf(m, __shfl_xor(m, 8));
        float sum = 0.f;
#pragma unroll
        for (int j = 0; j < 4; j++) {
            sv[r][j] = __expf(sv[r][j] - m);
            sum += sv[r][j];
        }
        sum += __shfl_xor(sum, 1);
        sum += __shfl_xor(sum, 2);
        sum += __shfl_xor(sum, 4);
        sum += __shfl_xor(sum, 8);
        float rinv = 1.f / sum;
#pragma unroll
        for (int j = 0; j < 4; j++)
            sPp[(lq * 4 + r) * 72 + j * 16 + ln] = f2bf(sv[r][j] * rinv);
    }
    // wave-private strip: no barrier needed

    o[0] = f32x4{0.f, 0.f, 0.f, 0.f};
    o[1] = f32x4{0.f, 0.f, 0.f, 0.f};
    o[2] = f32x4{0.f, 0.f, 0.f, 0.f};
    o[3] = f32x4{0.f, 0.f, 0.f, 0.f};
#pragma unroll
    for (int ks = 0; ks < 2; ks++) {
        bf16x8 a = *(const bf16x8*)&sPp[ln * 72 + ks * 32 + lq * 8];
#pragma unroll
        for (int jd = 0; jd < 4; jd++) {
            bf16x8 bb = *(const bf16x8*)&sVTp[(jd * 16 + ln) * 72 + ks * 32 + lq * 8];
            o[jd] = mfma16(a, bb, o[jd]);
        }
    }
}

// ---------------------------------------------------------------------------
// Windowed attention: block = (b, window, head-pair); grid 2048 x 256.
// Both tiles' global loads issued up-front (reg-staged); tile-1 loads stay in
// flight under tile-0 compute. Per-tile math identical to previous rounds.
// ---------------------------------------------------------------------------
__global__ __launch_bounds__(256) void attn_kernel(
    const u16* __restrict__ Q, const u16* __restrict__ K, const u16* __restrict__ VT,
    const float* __restrict__ biasf, u16* __restrict__ Out)
{
    __shared__ u16 sQ[2][64 * 72];   // each reused as output staging
    __shared__ u16 sK[2][64 * 72];
    __shared__ u16 sVT[2][64 * 72];  // [d][token]
    __shared__ u16 sP[2][4][16 * 72];

    const int tid = threadIdx.x;
    const int code0 = blockIdx.x << 1;       // head-pair: h0 even, h1 = h0+1
    const int h0 = code0 & 7;
    const int w = (code0 >> 3) & 63;
    const int b = code0 >> 9;
    const int lane = tid & 63, wave = tid >> 6;
    const int ln = lane & 15, lq = lane >> 4;

    const size_t qrow0 = (size_t)(b << 12) + w * 64;

    // issue ALL global loads (both tiles) up-front; T1 flies under T0 compute
    u16x8 rq[2][2], rk[2][2], rv[2][2];
#pragma unroll
    for (int t = 0; t < 2; ++t) {
        const int h = h0 + t;
        const size_t vrow0 = ((size_t)(((b << 3) + h) << 6)) * 4096 + w * 64;
#pragma unroll
        for (int ii = 0; ii < 2; ii++) {
            int idx = ii * 256 + tid;
            int rw = idx >> 3, ch = (idx & 7) << 3;
            size_t ga = (qrow0 + rw) * 512 + h * 64 + ch;
            rq[t][ii] = *(const u16x8*)&Q[ga];
            rk[t][ii] = *(const u16x8*)&K[ga];
            rv[t][ii] = *(const u16x8*)&VT[vrow0 + (size_t)rw * 4096 + ch];
        }
    }
#pragma unroll
    for (int ii = 0; ii < 2; ii++) {
        int idx = ii * 256 + tid;
        int rw = idx >> 3, ch = (idx & 7) << 3;
        *(u16x8*)&sQ[0][rw * 72 + ch] = rq[0][ii];
        *(u16x8*)&sK[0][rw * 72 + ch] = rk[0][ii];
        *(u16x8*)&sVT[0][rw * 72 + ch] = rv[0][ii];
    }
    __syncthreads();

    f32x4 o[4];
    attn_tile(sQ[0], sK[0], sVT[0], sP[0][wave], biasf, h0, wave, ln, lq, o);

    // write tile-1 LDS (loads landed during T0 compute)
#pragma unroll
    for (int ii = 0; ii < 2; ii++) {
        int idx = ii * 256 + tid;
        int rw = idx >> 3, ch = (idx & 7) << 3;
        *(u16x8*)&sQ[1][rw * 72 + ch] = rq[1][ii];
        *(u16x8*)&sK[1][rw * 72 + ch] = rk[1][ii];
        *(u16x8*)&sVT[1][rw * 72 + ch] = rv[1][ii];
    }
    // stage T0 output into sQ[0] (wave-local rows; wave's Q reads are done)
#pragma unroll
    for (int r = 0; r < 4; r++)
#pragma unroll
        for (int jd = 0; jd < 4; jd++)
            sQ[0][(wave * 16 + lq * 4 + r) * 72 + jd * 16 + ln] = f2bf(o[jd][r]);
    __syncthreads();

    // store T0 + compute T1
#pragma unroll
    for (int ii = 0; ii < 2; ii++) {
        int idx = ii * 256 + tid;
        int rw = idx >> 3, ch = (idx & 7) << 3;
        *(u16x8*)&Out[(qrow0 + rw) * 512 + h0 * 64 + ch] = *(const u16x8*)&sQ[0][rw * 72 + ch];
    }
    attn_tile(sQ[1], sK[1], sVT[1], sP[1][wave], biasf, h0 + 1, wave, ln, lq, o);
#pragma unroll
    for (int r = 0; r < 4; r++)
#pragma unroll
        for (int jd = 0; jd < 4; jd++)
            sQ[1][(wave * 16 + lq * 4 + r) * 72 + jd * 16 + ln] = f2bf(o[jd][r]);
    __syncthreads();
#pragma unroll
    for (int ii = 0; ii < 2; ii++) {
        int idx = ii * 256 + tid;
        int rw = idx >> 3, ch = (idx & 7) << 3;
        *(u16x8*)&Out[(qrow0 + rw) * 512 + (h0 + 1) * 64 + ch] =
            *(const u16x8*)&sQ[1][rw * 72 + ch];
    }
}

// ---------------------------------------------------------------------------
extern "C" void kernel_launch(void* const* d_in, const int* in_sizes, int n_in,
                              void* d_out, int out_size, void* d_ws, size_t ws_size,
                              hipStream_t stream)
{
    const float* q    = (const float*)d_in[0];
    const float* kv   = (const float*)d_in[1];
    const float* g_q  = (const float*)d_in[2];
    const float* b_q  = (const float*)d_in[3];
    const float* g_kv = (const float*)d_in[4];
    const float* b_kv = (const float*)d_in[5];
    const float* Wq   = (const float*)d_in[6];
    const float* bq   = (const float*)d_in[7];
    const float* Wk   = (const float*)d_in[8];
    const float* bk   = (const float*)d_in[9];
    const float* Wv   = (const float*)d_in[10];
    const float* bv   = (const float*)d_in[11];
    const float* Wo   = (const float*)d_in[12];
    const float* bo   = (const float*)d_in[13];
    const float* btab = (const float*)d_in[14];

    char* ws = (char*)d_ws;
    u16* qn      = (u16*)(ws);                 // 33,554,432 B  (permuted token order)
    u16* kvn     = (u16*)(ws + 33554432);      // 33,554,432 B  (reused as attn out)
    u16* VT      = (u16*)(ws + 67108864);      // 33,554,432 B  (b,h,d,wpos)
    float* rope  = (float*)(ws + 100663296);   // 1,048,576 B
    float* biasf = (float*)(ws + 101711872);   // 131,072 B
    u16* wq      = (u16*)(ws + 101842944);     // 4 x 524,288 B
    u16* wk      = (u16*)(ws + 102367232);
    u16* wv      = (u16*)(ws + 102891520);
    u16* wo      = (u16*)(ws + 103415808);
    u16* aout    = kvn;                        // safe: kvn consumed by QKV projection
    u16* Qr      = (u16*)d_out;                // d_out as scratch for Q/K (bf16)
    u16* Kr      = Qr + 16777216;

    prep_kernel<<<3712, 256, 0, stream>>>(q, kv, g_q, b_q, g_kv, b_kv,
                                          Wq, Wk, Wv, Wo, btab,
                                          qn, kvn, wq, wk, wv, wo, rope, biasf);
    gemm_qkv<<<768, 512, 0, stream>>>(qn, kvn, wq, wk, wv, bq, bk, bv, rope, Qr, Kr, VT);
    attn_kernel<<<2048, 256, 0, stream>>>(Qr, Kr, VT, biasf, aout);
    gemm_out<<<256, 512, 0, stream>>>(aout, wo, bo, qn, (float*)d_out);
}

// Round 9
// 344.590 us; speedup vs baseline: 1.1042x; 1.0156x over previous
//
#include <hip/hip_runtime.h>

// Problem: B=8, C=512, H=W=64, NH=8, D=64, window 8x8 (Ws=64), N=4096.
// Token dim is window-permuted AT THE LAYERNORM (bit-swap n[8:6]<->n[5:3], involution):
// qn/kvn/Q/K/V/attn-out all live in permuted space (windows contiguous); un-permute
// happens only in gemm_out's final transposed store. V stored transposed (b,h,d,wpos).
//
// Round-9: (1) attn REVERTED to round-5 1-tile form (r8 A/B showed the 2-tile pairing
// was a regression: LDS 36->72KB dropped residency 4->2 blocks/CU, losing the TLP that
// was hiding load latency). (2) gemm_qkv PERSISTENT: grid 768->256, each block runs its
// 3 tiles (same swz mapping); next tile's 8-load prologue issues right after the final
// loop barrier and flies under the current epilogue (sU moved to AY region, disjoint
// from prologue's AX/BX). vmcnt ledger re-derived with the 16 epilogue stores counted:
// warm items use vmcnt(20) at entry + it0-phase2; cold item 0 keeps vmcnt(4).
// gemm_out / prep unchanged from round 8 (controls).

typedef unsigned short u16;
typedef __bf16 bf16x8 __attribute__((ext_vector_type(8)));
typedef float f32x4 __attribute__((ext_vector_type(4)));
typedef float f32x2 __attribute__((ext_vector_type(2)));
typedef u16 u16x8 __attribute__((ext_vector_type(8)));
typedef u16 u16x4 __attribute__((ext_vector_type(4)));

__device__ __forceinline__ u16 f2bf(float f) {
    __bf16 h = (__bf16)f;
    return __builtin_bit_cast(u16, h);
}
__device__ __forceinline__ float bf2f(u16 u) {
    return (float)__builtin_bit_cast(__bf16, u);
}
__device__ __forceinline__ f32x4 mfma16(bf16x8 a, bf16x8 b, f32x4 c) {
    return __builtin_amdgcn_mfma_f32_16x16x32_bf16(a, b, c, 0, 0, 0);
}
__device__ __forceinline__ void gl_lds16(const u16* g, u16* l) {
    __builtin_amdgcn_global_load_lds((const __attribute__((address_space(1))) void*)g,
                                     (__attribute__((address_space(3))) void*)l, 16, 0, 0);
}
// window permutation: n = hn[11:9] r[8:6] wn[5:3] cc[2:0] -> hn wn r cc  (involution)
__device__ __forceinline__ int swapb(int n) {
    return (n & 0xE07) | ((n & 0x1C0) >> 3) | ((n & 0x038) << 3);
}

// ---------------------------------------------------------------------------
// prep_kernel: grid 3712 x 256. (unchanged from round 8)
//  blocks [0,1024):    LayerNorm q  -> qn   (permuted bf16)
//  blocks [1024,2048): LayerNorm kv -> kvn
//  blocks [2048,3072): weights f32->bf16, u16x4-vectorized (4 elems/thread)
//  blocks [3072,3584): RoPE table (1 sin/cos pair per thread, f32x2 store)
//  blocks [3584,3712): bias table
// ---------------------------------------------------------------------------
__global__ __launch_bounds__(256) void prep_kernel(
    const float* __restrict__ q, const float* __restrict__ kv,
    const float* __restrict__ g_q, const float* __restrict__ b_q,
    const float* __restrict__ g_kv, const float* __restrict__ b_kv,
    const float* __restrict__ Wq, const float* __restrict__ Wk,
    const float* __restrict__ Wv, const float* __restrict__ Wo,
    const float* __restrict__ btab,
    u16* __restrict__ qn, u16* __restrict__ kvn,
    u16* __restrict__ wq, u16* __restrict__ wk,
    u16* __restrict__ wv, u16* __restrict__ wo,
    float* __restrict__ rope, float* __restrict__ biasf)
{
    __shared__ u16 sX[512 * 36];  // [c][token], stride 36 (8B-aligned u16x4 stores)
    __shared__ float sS[1024];
    __shared__ float sQm[1024];
    __shared__ float sMu[32], sInv[32];

    const int bidx = blockIdx.x;
    const int tid = threadIdx.x;

    if (bidx >= 2048) {  // ---------------- setup roles ----------------
        if (bidx < 3072) {  // weights: 4 elems/thread, vectorized
            int idx = (bidx - 2048) * 256 + tid;       // [0, 262144)
            int w = idx >> 16, qd = idx & 65535;       // matrix, quad index
            const float* src = (w == 0) ? Wq : (w == 1) ? Wk : (w == 2) ? Wv : Wo;
            u16* dst = (w == 0) ? wq : (w == 1) ? wk : (w == 2) ? wv : wo;
            f32x4 v = *(const f32x4*)&src[qd * 4];
            u16x4 h;
#pragma unroll
            for (int r = 0; r < 4; r++) h[r] = f2bf(v[r]);
            *(u16x4*)&dst[qd * 4] = h;
        } else if (bidx < 3584) {  // rope
            int idx = (bidx - 3072) * 256 + tid;       // [0, 131072)
            int n = idx >> 5, j = idx & 31;
            float inv = powf(10000.0f, -(float)j / 32.0f);
            float a = (float)n * inv;
            float s, c;
            sincosf(a, &s, &c);
            f32x2 sc;
            sc[0] = s;
            sc[1] = c;
            *(f32x2*)&rope[n * 64 + 2 * j] = sc;
        } else {  // bias
            int idx = (bidx - 3584) * 256 + tid;       // [0, 32768)
            int qq = idx & 63, pp = (idx >> 6) & 63, h = idx >> 12;
            int r1 = pp >> 3, c1 = pp & 7, r2 = qq >> 3, c2 = qq & 7;
            int ri = (r1 - r2 + 7) * 15 + (c1 - c2 + 7);
            biasf[idx] = btab[ri * 8 + h];
        }
        return;
    }

    // ---------------- LayerNorm role ----------------
    const float* x  = (bidx < 1024) ? q : kv;
    const float* g  = (bidx < 1024) ? g_q : g_kv;
    const float* be = (bidx < 1024) ? b_q : b_kv;
    u16* out = (bidx < 1024) ? qn : kvn;
    const int bid = bidx & 1023;

    const int b = bid >> 7, grp = bid & 127;
    const int nbase = grp << 5;
    const int t4 = tid & 7;   // token quad (4 tokens each)
    const int cg = tid >> 3;  // 32 channels per iteration

    const float* xp = x + ((size_t)b << 21) + nbase + (t4 << 2);
    float sm[4] = {0.f, 0.f, 0.f, 0.f}, sq2[4] = {0.f, 0.f, 0.f, 0.f};
#pragma unroll 8
    for (int it = 0; it < 16; it++) {
        int c = (it << 5) + cg;
        f32x4 v = *(const f32x4*)&xp[(size_t)c << 12];
        u16x4 h;
#pragma unroll
        for (int r = 0; r < 4; r++) {
            sm[r] += v[r];
            sq2[r] += v[r] * v[r];
            h[r] = f2bf(v[r]);
        }
        *(u16x4*)&sX[c * 36 + (t4 << 2)] = h;
    }
#pragma unroll
    for (int r = 0; r < 4; r++) {
        sS[tid * 4 + r] = sm[r];
        sQm[tid * 4 + r] = sq2[r];
    }
    __syncthreads();
    if (tid < 32) {  // token tid: t4v = tid>>2, r = tid&3
        int t4v = tid >> 2, r = tid & 3;
        float a = 0.f, q2 = 0.f;
#pragma unroll
        for (int c2 = 0; c2 < 32; c2++) {
            int i2 = ((c2 << 3) + t4v) * 4 + r;
            a += sS[i2];
            q2 += sQm[i2];
        }
        float mu = a * (1.f / 512.f);
        float var = q2 * (1.f / 512.f) - mu * mu;
        sMu[tid] = mu;
        sInv[tid] = rsqrtf(var + 1e-5f);
    }
    __syncthreads();

    const int t = tid >> 3;         // 0..31
    const int cs = (tid & 7) << 3;  // 0..56
    float mu = sMu[t], inv = sInv[t];
    int p = swapb(nbase + t);  // permuted row
    size_t orow = ((size_t)((b << 12) + p)) * 512;
#pragma unroll
    for (int it = 0; it < 8; it++) {
        int c0 = cs + (it << 6);
        f32x4 g0 = *(const f32x4*)&g[c0];
        f32x4 g1 = *(const f32x4*)&g[c0 + 4];
        f32x4 e0 = *(const f32x4*)&be[c0];
        f32x4 e1 = *(const f32x4*)&be[c0 + 4];
        u16x8 o;
#pragma unroll
        for (int k = 0; k < 8; k++) {
            float v = bf2f(sX[(c0 + k) * 36 + t]);
            float gg = (k < 4) ? g0[k] : g1[k - 4];
            float bb = (k < 4) ? e0[k] : e1[k - 4];
            o[k] = f2bf((v - mu) * inv * gg + bb);
        }
        *(u16x8*)&out[orow + c0] = o;
    }
}

// ---------------------------------------------------------------------------
// Shared 8-phase 256x256 / BK=64 / 8-wave main-loop machinery (round-4 verified),
// refactored: PROLOGUE4 split out; STAGE takes the global pointer; MAIN_LOOP takes
// WARM (persistent-kernel items >0 have 16 older epilogue stores in the vmcnt
// stream -> entry and it0-phase2 gates become vmcnt(20); ledger verified op-by-op).
// ---------------------------------------------------------------------------
#define SB() __builtin_amdgcn_sched_barrier(0)
#define BARRIER() do { SB(); __builtin_amdgcn_s_barrier(); SB(); } while (0)
#define VM4() asm volatile("s_waitcnt vmcnt(4)" ::: "memory")
#define VM0() asm volatile("s_waitcnt vmcnt(0)" ::: "memory")
#define VM20() asm volatile("s_waitcnt vmcnt(20)" ::: "memory")
#define STAGE_P(ptr, base, kt, kk) do { \
        const u16* _g = (ptr) + (kt) * 64 + (kk) * 32; \
        gl_lds16(_g, &smem[(base) + (kk) * 8192 + wid * 512]); \
        gl_lds16(_g + 65536, &smem[(base) + (kk) * 8192 + 4096 + wid * 512]); \
    } while (0)
#define PROLOGUE4(aP, bP) do { \
        STAGE_P(aP, AX, 0, 0); \
        STAGE_P(bP, BX, 0, 0); \
        STAGE_P(aP, AX, 0, 1); \
        STAGE_P(bP, BX, 0, 1); \
    } while (0)
#define LDA(base, kk, mh) do { \
        Af[0] = *(const bf16x8*)&smem[(base) + (kk) * 8192 + (mh) * 2048 + 0 * 512 + aOff]; \
        Af[1] = *(const bf16x8*)&smem[(base) + (kk) * 8192 + (mh) * 2048 + 1 * 512 + aOff]; \
        Af[2] = *(const bf16x8*)&smem[(base) + (kk) * 8192 + (mh) * 2048 + 2 * 512 + aOff]; \
        Af[3] = *(const bf16x8*)&smem[(base) + (kk) * 8192 + (mh) * 2048 + 3 * 512 + aOff]; \
    } while (0)
#define LDB(base, kk) do { \
        Bf[0] = *(const bf16x8*)&smem[(base) + (kk) * 8192 + 0 * 512 + bOff]; \
        Bf[1] = *(const bf16x8*)&smem[(base) + (kk) * 8192 + 1 * 512 + bOff]; \
        Bf[2] = *(const bf16x8*)&smem[(base) + (kk) * 8192 + 2 * 512 + bOff]; \
        Bf[3] = *(const bf16x8*)&smem[(base) + (kk) * 8192 + 3 * 512 + bOff]; \
    } while (0)
#define MMA(mh) do { \
        __builtin_amdgcn_s_setprio(1); \
        _Pragma("unroll") \
        for (int fi = 0; fi < 4; ++fi) \
            _Pragma("unroll") \
            for (int j = 0; j < 4; ++j) \
                acc[(mh) * 4 + fi][j] = mfma16(Af[fi], Bf[j], acc[(mh) * 4 + fi][j]); \
        __builtin_amdgcn_s_setprio(0); \
    } while (0)

#define MAIN_LOOP_8PHASE(WARM) \
    if (WARM) { VM20(); } else { VM4(); } \
    BARRIER(); \
    _Pragma("unroll") \
    for (int it = 0; it < 4; ++it) { \
        const bool last = (it == 3); \
        bf16x8 Af[4], Bf[4]; \
        LDA(AX, 0, 0); LDB(BX, 0); STAGE_P(aSt, AY, 2 * it + 1, 0); \
        BARRIER(); MMA(0); BARRIER(); \
        LDA(AX, 0, 1); STAGE_P(bSt, BY, 2 * it + 1, 0); \
        BARRIER(); MMA(1); \
        if ((WARM) && it == 0) { VM20(); } else { VM4(); } \
        BARRIER(); \
        LDA(AX, 1, 0); LDB(BX, 1); STAGE_P(aSt, AY, 2 * it + 1, 1); \
        BARRIER(); MMA(0); BARRIER(); \
        LDA(AX, 1, 1); STAGE_P(bSt, BY, 2 * it + 1, 1); \
        BARRIER(); MMA(1); VM4(); BARRIER(); \
        LDA(AY, 0, 0); LDB(BY, 0); if (!last) STAGE_P(aSt, AX, 2 * it + 2, 0); \
        BARRIER(); MMA(0); BARRIER(); \
        LDA(AY, 0, 1); if (!last) STAGE_P(bSt, BX, 2 * it + 2, 0); \
        BARRIER(); MMA(1); \
        if (!last) { VM4(); } else { VM0(); } \
        BARRIER(); \
        LDA(AY, 1, 0); LDB(BY, 1); if (!last) STAGE_P(aSt, AX, 2 * it + 2, 1); \
        BARRIER(); MMA(0); BARRIER(); \
        LDA(AY, 1, 1); if (!last) STAGE_P(bSt, BX, 2 * it + 2, 1); \
        BARRIER(); MMA(1); if (!last) VM4(); BARRIER(); \
    }

// ---------------------------------------------------------------------------
// Fused Q/K/V projection, persistent 8-phase core. grid 256 (1 block/CU); each
// block runs items 0..2 with virtual id = item*256 + blockIdx.x through the same
// XCD-swizzled mapping as before. Next item's prologue (AX/BX) issues right after
// the final loop barrier, flying under the current epilogue (sU in AY region).
// Q/K epilogue applies RoPE (n = swapb(row)); V epilogue writes (b,h,d,wpos).
// ---------------------------------------------------------------------------
__global__ __launch_bounds__(512, 2) void gemm_qkv(
    const u16* __restrict__ qn, const u16* __restrict__ kvn,
    const u16* __restrict__ wq, const u16* __restrict__ wk, const u16* __restrict__ wv,
    const float* __restrict__ bq, const float* __restrict__ bk, const float* __restrict__ bv,
    const float* __restrict__ rope,
    u16* __restrict__ Qr, u16* __restrict__ Kr, u16* __restrict__ VT)
{
    __shared__ __align__(16) u16 smem[65536];  // 128 KB

    const int p = blockIdx.x;  // 0..255
    const int tid = threadIdx.x;
    const int lane = tid & 63, wid = tid >> 6;
    const int ln = lane & 15, lq = lane >> 4;
    const int wr = wid >> 2, wc = wid & 3;  // wave -> (2M x 4N) sub-tile

    const int rr = tid >> 2;
    const int cc = (tid & 3) ^ ((tid >> 3) & 3);

    const int AX = 0, BX = 16384, AY = 32768, BY = 49152;
    const int swzc = lq ^ ((ln >> 1) & 3);
    const int aOff = wr * 4096 + ln * 32 + swzc * 8;
    const int bOff = wc * 2048 + ln * 32 + swzc * 8;

    const u16* aSt;
    const u16* bSt;
    const float* bias;
    int kind, n0, m0;

#define DECODE(VID) do { \
        int _swz = ((VID) & 7) * 96 + ((VID) >> 3); \
        kind = _swz >> 8; \
        int _rem = _swz & 255; \
        n0 = (_rem >> 7) << 8; \
        m0 = (_rem & 127) << 8; \
        const u16* _As = (kind == 0) ? qn : kvn; \
        const u16* _W = (kind == 0) ? wq : (kind == 1) ? wk : wv; \
        bias = (kind == 0) ? bq : (kind == 1) ? bk : bv; \
        aSt = _As + (size_t)(m0 + rr) * 512 + cc * 8; \
        bSt = _W + (size_t)(n0 + rr) * 512 + cc * 8; \
    } while (0)

    f32x4 acc[8][4];

    DECODE(p);
    PROLOGUE4(aSt, bSt);

#pragma unroll 1
    for (int item = 0; item < 3; ++item) {
#pragma unroll
        for (int i = 0; i < 8; ++i)
#pragma unroll
            for (int j = 0; j < 4; ++j) acc[i][j] = f32x4{0.f, 0.f, 0.f, 0.f};

        const bool warm = (item != 0);
        MAIN_LOOP_8PHASE(warm);

        // save current epilogue params, then issue NEXT tile's prologue (AX/BX —
        // disjoint from epilogue's sU in AY); its latency hides under the epilogue.
        const int ek = kind, en0 = n0, em0 = m0;
        const float* ebias = bias;
        if (item < 2) {
            DECODE((item + 1) * 256 + p);
            PROLOGUE4(aSt, bSt);
        }

        // ------------------------- epilogue (sU in AY region) -------------------------
        float bj[4];
#pragma unroll
        for (int j = 0; j < 4; ++j) bj[j] = ebias[en0 + wc * 64 + j * 16 + ln];

        u16* sU = smem + 32768;  // 64 x 264 u16 staging; spans [32768,49664) < 65536

        if (ek < 2) {
            u16* Out = (ek == 0) ? Qr : Kr;
#pragma unroll
            for (int g = 0; g < 4; ++g) {  // row-groups of 64 tokens
                __syncthreads();
                if (wr == (g >> 1)) {
                    const int i0 = (g & 1) * 4;
#pragma unroll
                    for (int di = 0; di < 4; ++di)
#pragma unroll
                        for (int j = 0; j < 4; ++j)
#pragma unroll
                            for (int r = 0; r < 4; ++r)
                                sU[(di * 16 + lq * 4 + r) * 264 + wc * 64 + j * 16 + ln] =
                                    f2bf(acc[i0 + di][j][r] + bj[j]);
                }
                __syncthreads();
#pragma unroll
                for (int it = 0; it < 4; ++it) {
                    int idx = it * 512 + tid;
                    int row = idx >> 5;
                    int cseg = (idx & 31) << 3;
                    u16x8 v = *(const u16x8*)&sU[row * 264 + cseg];
                    int t = em0 + g * 64 + row;  // permuted row id (incl. batch)
                    int n = swapb(t & 4095);     // original token for RoPE
                    float f[8];
#pragma unroll
                    for (int k = 0; k < 8; k++) f[k] = bf2f(v[k]);
                    {
                        int d0 = cseg & 63;
                        const float* rp = &rope[n * 64 + d0];
                        f32x4 r0 = *(const f32x4*)rp;
                        f32x4 r1 = *(const f32x4*)(rp + 4);
#pragma unroll
                        for (int pp = 0; pp < 4; pp++) {
                            float sn = (pp < 2) ? r0[2 * pp] : r1[2 * (pp - 2)];
                            float cs2 = (pp < 2) ? r0[2 * pp + 1] : r1[2 * (pp - 2) + 1];
                            float x0 = f[2 * pp], x1 = f[2 * pp + 1];
                            f[2 * pp] = x0 * cs2 - x1 * sn;
                            f[2 * pp + 1] = x0 * sn + x1 * cs2;
                        }
                    }
                    u16x8 o;
#pragma unroll
                    for (int k = 0; k < 8; k++) o[k] = f2bf(f[k]);
                    *(u16x8*)&Out[(size_t)t * 512 + en0 + cseg] = o;
                }
            }
        } else {
            const int wq0 = em0 & 4095;
            const int bb = em0 >> 12;
#pragma unroll
            for (int g = 0; g < 4; ++g) {  // channel-groups of 64
                __syncthreads();
                if (wc == g) {  // 2 waves (wr 0,1) write their full acc transposed
#pragma unroll
                    for (int i = 0; i < 8; ++i)
#pragma unroll
                        for (int j = 0; j < 4; ++j) {
                            u16x4 pk;
#pragma unroll
                            for (int r = 0; r < 4; ++r) pk[r] = f2bf(acc[i][j][r] + bj[j]);
                            *(u16x4*)&sU[(j * 16 + ln) * 264 + wr * 128 + i * 16 + lq * 4] = pk;
                        }
                }
                __syncthreads();
#pragma unroll
                for (int it = 0; it < 4; ++it) {
                    int idx = it * 512 + tid;
                    int col = idx >> 5;          // channel within group
                    int ch = (idx & 31) << 3;    // token chunk
                    u16x8 v = *(const u16x8*)&sU[col * 264 + ch];
                    int c = en0 + g * 64 + col;
                    int hh = c >> 6, dd = c & 63;
                    *(u16x8*)&VT[((size_t)((((bb << 3) + hh) << 6) + dd)) * 4096 + wq0 + ch] = v;
                }
            }
        }
    }
#undef DECODE
}

// ---------------------------------------------------------------------------
// Output projection, 8-phase 256^2 core. grid 256, XCD-swizzled. (r8 logic,
// refactored onto the shared macros; single item, cold gates.)
// Epilogue: per 64-col group, stage residual + deposit acc+bias+res into
// 256x65 f32 LDS, then store swapb-runs of 32 contiguous tokens (128B lines).
// ---------------------------------------------------------------------------
__global__ __launch_bounds__(512, 2) void gemm_out(
    const u16* __restrict__ A, const u16* __restrict__ Bw,
    const float* __restrict__ bias, const u16* __restrict__ qn,
    float* __restrict__ Out)
{
    __shared__ __align__(16) u16 smem[65536];  // 128 KB

    const int bid = blockIdx.x;
    const int swz = (bid & 7) * 32 + (bid >> 3);  // 256 % 8 == 0 -> bijective
    const int n0 = (swz >> 7) << 8;   // 0 or 256
    const int m0 = (swz & 127) << 8;  // 0..32512

    const int tid = threadIdx.x;
    const int lane = tid & 63, wid = tid >> 6;
    const int ln = lane & 15, lq = lane >> 4;
    const int wr = wid >> 2, wc = wid & 3;

    const int rr = tid >> 2;
    const int cc = (tid & 3) ^ ((tid >> 3) & 3);
    const u16* aSt = A + (size_t)(m0 + rr) * 512 + cc * 8;
    const u16* bSt = Bw + (size_t)(n0 + rr) * 512 + cc * 8;

    const int AX = 0, BX = 16384, AY = 32768, BY = 49152;
    const int swzc = lq ^ ((ln >> 1) & 3);
    const int aOff = wr * 4096 + ln * 32 + swzc * 8;
    const int bOff = wc * 2048 + ln * 32 + swzc * 8;

    f32x4 acc[8][4] = {};

    PROLOGUE4(aSt, bSt);
    MAIN_LOOP_8PHASE(false);

    // ------------------------- epilogue -------------------------
    // Within this 256-row tile (m0 multiple of 256), for any fixed channel the
    // un-permuted tokens nb = swapb(m0l + i) form 8 runs (r3 = i[5:3]) of 32
    // contiguous tokens: run base = swapb(m0l) + r3*64, offset o = i[7:6]<<3 | i[2:0].
    // Inverse used by the store: o = op*4 + r  ->  i = ((op&1)<<2 | r) + r3*8 + (op>>1)*64.
    float bj[4];
#pragma unroll
    for (int j = 0; j < 4; ++j) bj[j] = bias[n0 + wc * 64 + j * 16 + ln];

    float* sOutF = (float*)smem;            // 256 x 65 f32 (66,560 B)
    u16* sRes = smem + 33280;               // byte 66,560: 256 x 72 u16 (36,864 B)
    const int bb = m0 >> 12;
    const int swb = swapb(m0 & 4095);
    const size_t outBase = ((size_t)((bb << 9) + n0)) << 12;

#pragma unroll
    for (int cg = 0; cg < 4; ++cg) {
        __syncthreads();
        // stage residual 256 rows x 64 cols (coalesced u16x8)
#pragma unroll
        for (int itq = 0; itq < 4; ++itq) {
            int idx = itq * 512 + tid;
            int row = idx >> 3, c8 = (idx & 7) << 3;
            *(u16x8*)&sRes[row * 72 + c8] =
                *(const u16x8*)&qn[(size_t)(m0 + row) * 512 + n0 + cg * 64 + c8];
        }
        __syncthreads();
        if (wc == cg) {  // 2 waves (wr 0,1) deposit acc + bias + residual
#pragma unroll
            for (int i = 0; i < 8; ++i)
#pragma unroll
                for (int j = 0; j < 4; ++j)
#pragma unroll
                    for (int r = 0; r < 4; ++r) {
                        int row = wr * 128 + i * 16 + lq * 4 + r;
                        int c = j * 16 + ln;
                        sOutF[row * 65 + c] =
                            acc[i][j][r] + bj[j] + bf2f(sRes[row * 72 + c]);
                    }
        }
        __syncthreads();
        // coalesced store: per wave, one channel per li; 8 lanes cover one 128B run
#pragma unroll
        for (int li = 0; li < 8; ++li) {
            int u = li * 512 + tid;
            int c = u >> 6, r3 = (u >> 3) & 7, op = u & 7;
            int base_i = ((op & 1) << 2) + (r3 << 3) + ((op >> 1) << 6);
            f32x4 v;
#pragma unroll
            for (int r = 0; r < 4; ++r) v[r] = sOutF[(base_i + r) * 65 + c];
            *(f32x4*)&Out[outBase + ((size_t)(cg * 64 + c) << 12) + swb + r3 * 64 + op * 4] = v;
        }
    }
}

#undef SB
#undef BARRIER
#undef VM4
#undef VM0
#undef VM20
#undef STAGE_P
#undef PROLOGUE4
#undef LDA
#undef LDB
#undef MMA
#undef MAIN_LOOP_8PHASE

// ---------------------------------------------------------------------------
// Windowed attention: block = (b, window, head); all inputs window-contiguous.
// grid 4096: h = bid&7, w = (bid>>3)&63, b = bid>>9.  (round-5 form: 36KB LDS,
// 4 blocks/CU residency — cross-block TLP hides load latency.)
// ---------------------------------------------------------------------------
__global__ __launch_bounds__(256) void attn_kernel(
    const u16* __restrict__ Q, const u16* __restrict__ K, const u16* __restrict__ VT,
    const float* __restrict__ biasf, u16* __restrict__ Out)
{
    __shared__ u16 sQ[64 * 72];   // reused as output staging
    __shared__ u16 sK[64 * 72];
    __shared__ u16 sVT[64 * 72];  // [d][token]
    __shared__ u16 sP[4][16 * 72];

    const int tid = threadIdx.x;
    const int h = blockIdx.x & 7;
    const int w = (blockIdx.x >> 3) & 63;
    const int b = blockIdx.x >> 9;
    const int lane = tid & 63, wave = tid >> 6;
    const int ln = lane & 15, lq = lane >> 4;

    const size_t qrow0 = (size_t)(b << 12) + w * 64;
    const size_t vrow0 = ((size_t)(((b << 3) + h) << 6)) * 4096 + w * 64;

#pragma unroll
    for (int ii = 0; ii < 2; ii++) {
        int idx = ii * 256 + tid;
        int row = idx >> 3, ch = (idx & 7) << 3;
        size_t ga = (qrow0 + row) * 512 + h * 64 + ch;
        *(u16x8*)&sQ[row * 72 + ch] = *(const u16x8*)&Q[ga];
        *(u16x8*)&sK[row * 72 + ch] = *(const u16x8*)&K[ga];
        *(u16x8*)&sVT[row * 72 + ch] = *(const u16x8*)&VT[vrow0 + (size_t)row * 4096 + ch];
    }
    __syncthreads();

    f32x4 s[4] = {};
#pragma unroll
    for (int ks = 0; ks < 2; ks++) {
        bf16x8 a = *(const bf16x8*)&sQ[(wave * 16 + ln) * 72 + ks * 32 + lq * 8];
#pragma unroll
        for (int j = 0; j < 4; j++) {
            bf16x8 bb = *(const bf16x8*)&sK[(j * 16 + ln) * 72 + ks * 32 + lq * 8];
            s[j] = mfma16(a, bb, s[j]);
        }
    }

    float sv[4][4];
#pragma unroll
    for (int r = 0; r < 4; r++) {
        const float* bp = &biasf[((h * 64 + wave * 16 + lq * 4 + r) << 6) + ln];
#pragma unroll
        for (int j = 0; j < 4; j++) sv[r][j] = s[j][r] * 0.125f + bp[j * 16];
    }
#pragma unroll
    for (int r = 0; r < 4; r++) {
        float m = fmaxf(fmaxf(sv[r][0], sv[r][1]), fmaxf(sv[r][2], sv[r][3]));
        m = fmaxf(m, __shfl_xor(m, 1));
        m = fmaxf(m, __shfl_xor(m, 2));
        m = fmaxf(m, __shfl_xor(m, 4));
        m = fmaxf(m, __shfl_xor(m, 8));
        float sum = 0.f;
#pragma unroll
        for (int j = 0; j < 4; j++) {
            sv[r][j] = __expf(sv[r][j] - m);
            sum += sv[r][j];
        }
        sum += __shfl_xor(sum, 1);
        sum += __shfl_xor(sum, 2);
        sum += __shfl_xor(sum, 4);
        sum += __shfl_xor(sum, 8);
        float rinv = 1.f / sum;
#pragma unroll
        for (int j = 0; j < 4; j++)
            sP[wave][(lq * 4 + r) * 72 + j * 16 + ln] = f2bf(sv[r][j] * rinv);
    }
    // wave-private strip: no barrier needed

    f32x4 o[4] = {};
#pragma unroll
    for (int ks = 0; ks < 2; ks++) {
        bf16x8 a = *(const bf16x8*)&sP[wave][ln * 72 + ks * 32 + lq * 8];
#pragma unroll
        for (int jd = 0; jd < 4; jd++) {
            bf16x8 bb = *(const bf16x8*)&sVT[(jd * 16 + ln) * 72 + ks * 32 + lq * 8];
            o[jd] = mfma16(a, bb, o[jd]);
        }
    }

#pragma unroll
    for (int r = 0; r < 4; r++)
#pragma unroll
        for (int jd = 0; jd < 4; jd++)
            sQ[(wave * 16 + lq * 4 + r) * 72 + jd * 16 + ln] = f2bf(o[jd][r]);
    __syncthreads();
#pragma unroll
    for (int ii = 0; ii < 2; ii++) {
        int idx = ii * 256 + tid;
        int row = idx >> 3, ch = (idx & 7) << 3;
        *(u16x8*)&Out[(qrow0 + row) * 512 + h * 64 + ch] = *(const u16x8*)&sQ[row * 72 + ch];
    }
}

// ---------------------------------------------------------------------------
extern "C" void kernel_launch(void* const* d_in, const int* in_sizes, int n_in,
                              void* d_out, int out_size, void* d_ws, size_t ws_size,
                              hipStream_t stream)
{
    const float* q    = (const float*)d_in[0];
    const float* kv   = (const float*)d_in[1];
    const float* g_q  = (const float*)d_in[2];
    const float* b_q  = (const float*)d_in[3];
    const float* g_kv = (const float*)d_in[4];
    const float* b_kv = (const float*)d_in[5];
    const float* Wq   = (const float*)d_in[6];
    const float* bq   = (const float*)d_in[7];
    const float* Wk   = (const float*)d_in[8];
    const float* bk   = (const float*)d_in[9];
    const float* Wv   = (const float*)d_in[10];
    const float* bv   = (const float*)d_in[11];
    const float* Wo   = (const float*)d_in[12];
    const float* bo   = (const float*)d_in[13];
    const float* btab = (const float*)d_in[14];

    char* ws = (char*)d_ws;
    u16* qn      = (u16*)(ws);                 // 33,554,432 B  (permuted token order)
    u16* kvn     = (u16*)(ws + 33554432);      // 33,554,432 B  (reused as attn out)
    u16* VT      = (u16*)(ws + 67108864);      // 33,554,432 B  (b,h,d,wpos)
    float* rope  = (float*)(ws + 100663296);   // 1,048,576 B
    float* biasf = (float*)(ws + 101711872);   // 131,072 B
    u16* wq      = (u16*)(ws + 101842944);     // 4 x 524,288 B
    u16* wk      = (u16*)(ws + 102367232);
    u16* wv      = (u16*)(ws + 102891520);
    u16* wo      = (u16*)(ws + 103415808);
    u16* aout    = kvn;                        // safe: kvn consumed by QKV projection
    u16* Qr      = (u16*)d_out;                // d_out as scratch for Q/K (bf16)
    u16* Kr      = Qr + 16777216;

    prep_kernel<<<3712, 256, 0, stream>>>(q, kv, g_q, b_q, g_kv, b_kv,
                                          Wq, Wk, Wv, Wo, btab,
                                          qn, kvn, wq, wk, wv, wo, rope, biasf);
    gemm_qkv<<<256, 512, 0, stream>>>(qn, kvn, wq, wk, wv, bq, bk, bv, rope, Qr, Kr, VT);
    attn_kernel<<<4096, 256, 0, stream>>>(Qr, Kr, VT, biasf, aout);
    gemm_out<<<256, 512, 0, stream>>>(aout, wo, bo, qn, (float*)d_out);
}